// Round 1
// baseline (2013.619 us; speedup 1.0000x reference)
//
#include <hip/hip_runtime.h>
#include <math.h>

#define NN 50000
#define EE 800000
#define BB 500
#define LL 42
#define NHEAD 10
#define FH 35
#define FG 350
#define ETOT (EE + NN)
#define NCHUNK ((NN + 511) / 512)

__device__ __forceinline__ float lrelu(float x) { return x > 0.f ? x : 0.2f * x; }

// ---------------- graph prep ----------------
__global__ __launch_bounds__(256) void k_init(int* deg, int* cur) {
    int i = blockIdx.x * 256 + threadIdx.x;
    if (i < NN) { deg[i] = 1; cur[i] = 0; }   // deg=1 accounts for the self-loop
}

__global__ __launch_bounds__(256) void k_deg(const int* __restrict__ ei, int* deg) {
    int i = blockIdx.x * 256 + threadIdx.x;
    if (i < EE) atomicAdd(&deg[ei[EE + i]], 1);
}

__global__ __launch_bounds__(512) void k_scan1(const int* __restrict__ deg, int* part) {
    int i = blockIdx.x * 512 + threadIdx.x;
    int lane = threadIdx.x & 63, wv = threadIdx.x >> 6;
    int x = (i < NN) ? deg[i] : 0;
    #pragma unroll
    for (int d = 32; d; d >>= 1) x += __shfl_xor(x, d);
    __shared__ int wsum[8];
    if (lane == 0) wsum[wv] = x;
    __syncthreads();
    if (threadIdx.x == 0) {
        int s = 0;
        #pragma unroll
        for (int w = 0; w < 8; w++) s += wsum[w];
        part[blockIdx.x] = s;
    }
}

__global__ __launch_bounds__(64) void k_scan2(const int* __restrict__ part, int* pscan) {
    int l = threadIdx.x;
    int v0 = (l < NCHUNK) ? part[l] : 0;
    #pragma unroll
    for (int d = 1; d < 64; d <<= 1) { int t = __shfl_up(v0, d); if (l >= d) v0 += t; }
    int tot0 = __shfl(v0, 63);
    int v1 = (64 + l < NCHUNK) ? part[64 + l] : 0;
    #pragma unroll
    for (int d = 1; d < 64; d <<= 1) { int t = __shfl_up(v1, d); if (l >= d) v1 += t; }
    v1 += tot0;
    if (l < NCHUNK) pscan[l] = v0;
    if (64 + l < NCHUNK) pscan[64 + l] = v1;
}

__global__ __launch_bounds__(512) void k_scan3(const int* __restrict__ deg, const int* __restrict__ pscan,
                                               int* offs) {
    int i = blockIdx.x * 512 + threadIdx.x;
    int lane = threadIdx.x & 63, wv = threadIdx.x >> 6;
    int x = (i < NN) ? deg[i] : 0;
    int incl = x;
    #pragma unroll
    for (int d = 1; d < 64; d <<= 1) { int t = __shfl_up(incl, d); if (lane >= d) incl += t; }
    __shared__ int wtot[8];
    if (lane == 63) wtot[wv] = incl;
    __syncthreads();
    int woff = 0;
    for (int w = 0; w < wv; w++) woff += wtot[w];
    int base = (blockIdx.x == 0) ? 0 : pscan[blockIdx.x - 1];
    if (i < NN) offs[i] = base + woff + incl - x;   // exclusive prefix
}

__global__ __launch_bounds__(256) void k_scatter(const int* __restrict__ ei, const int* __restrict__ offs,
                                                 int* cur, int* csr_src, int* csr_eid) {
    int i = blockIdx.x * 256 + threadIdx.x;
    if (i < EE) {
        int s = ei[i], d = ei[EE + i];
        int slot = atomicAdd(&cur[d], 1);
        int p = offs[d] + slot;
        csr_src[p] = s;
        csr_eid[p] = i;
    } else if (i < ETOT) {
        int v = i - EE;
        int slot = atomicAdd(&cur[v], 1);
        int p = offs[v] + slot;
        csr_src[p] = v;
        csr_eid[p] = i;   // self-loop edge id = EE + v
    }
}

__global__ __launch_bounds__(256) void k_dinv(const int* __restrict__ deg, float* dinv) {
    int i = blockIdx.x * 256 + threadIdx.x;
    if (i < NN) dinv[i] = rsqrtf((float)deg[i]);
}

// ---------------- generic f32 tiled GEMM: C = act(A[M,K] @ B[K,N] + bias) ----------------
__global__ __launch_bounds__(256) void k_gemm(const float* __restrict__ A, const float* __restrict__ B,
                                              const float* __restrict__ bias, float* __restrict__ C,
                                              int M, int N, int K, int ldc, int act) {
    __shared__ float As[64][33];
    __shared__ __align__(16) float Bs[32][68];
    int tid = threadIdx.x;
    int tx = tid & 15, ty = tid >> 4;
    int m_base = blockIdx.y * 64, n_base = blockIdx.x * 64;
    float acc[4][4] = {};
    for (int k0 = 0; k0 < K; k0 += 32) {
        #pragma unroll
        for (int l = 0; l < 8; l++) {
            int idx = tid + l * 256;
            int i = idx >> 5, j = idx & 31;           // As[i(m)][j(k)]
            int gm = m_base + i, gk = k0 + j;
            As[i][j] = (gm < M && gk < K) ? A[(size_t)gm * K + gk] : 0.f;
        }
        #pragma unroll
        for (int l = 0; l < 8; l++) {
            int idx = tid + l * 256;
            int kk = idx >> 6, n = idx & 63;          // Bs[kk][n]
            int gk = k0 + kk, gn = n_base + n;
            Bs[kk][n] = (gk < K && gn < N) ? B[(size_t)gk * N + gn] : 0.f;
        }
        __syncthreads();
        #pragma unroll
        for (int kk = 0; kk < 32; kk++) {
            float4 b4 = *(const float4*)&Bs[kk][tx * 4];
            float a0 = As[ty * 4 + 0][kk];
            float a1 = As[ty * 4 + 1][kk];
            float a2 = As[ty * 4 + 2][kk];
            float a3 = As[ty * 4 + 3][kk];
            acc[0][0] += a0 * b4.x; acc[0][1] += a0 * b4.y; acc[0][2] += a0 * b4.z; acc[0][3] += a0 * b4.w;
            acc[1][0] += a1 * b4.x; acc[1][1] += a1 * b4.y; acc[1][2] += a1 * b4.z; acc[1][3] += a1 * b4.w;
            acc[2][0] += a2 * b4.x; acc[2][1] += a2 * b4.y; acc[2][2] += a2 * b4.z; acc[2][3] += a2 * b4.w;
            acc[3][0] += a3 * b4.x; acc[3][1] += a3 * b4.y; acc[3][2] += a3 * b4.z; acc[3][3] += a3 * b4.w;
        }
        __syncthreads();
    }
    #pragma unroll
    for (int r = 0; r < 4; r++) {
        int m = m_base + ty * 4 + r;
        if (m >= M) continue;
        #pragma unroll
        for (int c = 0; c < 4; c++) {
            int n = n_base + tx * 4 + c;
            if (n >= N) continue;
            float v = acc[r][c];
            if (bias) v += bias[n];
            if (act) v = fmaxf(v, 0.f);
            C[(size_t)m * ldc + n] = v;
        }
    }
}

// ---------------- GAT attention logits ----------------
__global__ __launch_bounds__(256) void k_att(const float* __restrict__ h, const float* __restrict__ att_s,
                                             const float* __restrict__ att_d, float* __restrict__ a_s,
                                             float* __restrict__ a_d) {
    int tid = blockIdx.x * 256 + threadIdx.x;
    if (tid >= NN * NHEAD) return;
    int n = tid / NHEAD, hd = tid % NHEAD;
    const float* hr = h + (size_t)n * FG + hd * FH;
    const float* ws = att_s + hd * FH;
    const float* wd = att_d + hd * FH;
    float as = 0.f, ad = 0.f;
    #pragma unroll
    for (int c = 0; c < FH; c++) { float v = hr[c]; as += v * ws[c]; ad += v * wd[c]; }
    a_s[tid] = as;
    a_d[tid] = ad;
}

// ---------------- GAT aggregate: wave per node ----------------
__global__ __launch_bounds__(256) void k_gat_agg(const float* __restrict__ h, const float* __restrict__ a_s,
                                                 const float* __restrict__ a_d,
                                                 const int* __restrict__ csr_src, const int* __restrict__ csr_eid,
                                                 const int* __restrict__ offs, const int* __restrict__ deg,
                                                 const float* __restrict__ b_gat,
                                                 float* __restrict__ xg, float* __restrict__ alphaOut) {
    int wid = (blockIdx.x * blockDim.x + threadIdx.x) >> 6;
    int lane = threadIdx.x & 63;
    if (wid >= NN) return;
    int o0 = offs[wid], d = deg[wid];
    bool mine = (lane < NHEAD);
    float adv = mine ? a_d[wid * NHEAD + lane] : 0.f;
    // pass 1: per-head max (lanes 0..9)
    float m = -1e30f;
    for (int i = 0; i < d; i++) {
        int s = csr_src[o0 + i];
        if (mine) m = fmaxf(m, lrelu(a_s[s * NHEAD + lane] + adv));
    }
    // pass 2: denominator
    float den = 0.f;
    for (int i = 0; i < d; i++) {
        int s = csr_src[o0 + i];
        if (mine) den += __expf(lrelu(a_s[s * NHEAD + lane] + adv) - m);
    }
    float rden = 1.f / (den + 1e-16f);
    // pass 3: alpha + weighted aggregate (all lanes own features)
    int f0 = lane, f1 = lane + 64, f2 = lane + 128, f3 = lane + 192, f4 = lane + 256, f5 = lane + 320;
    int h0 = f0 / 35, h1 = f1 / 35, h2 = f2 / 35, h3 = f3 / 35, h4 = f4 / 35;
    int h5 = (f5 < FG) ? (f5 / 35) : 0;
    float ac0 = 0, ac1 = 0, ac2 = 0, ac3 = 0, ac4 = 0, ac5 = 0;
    for (int i = 0; i < d; i++) {
        int s = csr_src[o0 + i];
        int eid = csr_eid[o0 + i];
        float al = 0.f;
        if (mine) {
            float e = lrelu(a_s[s * NHEAD + lane] + adv);
            al = __expf(e - m) * rden;
            alphaOut[(size_t)eid * NHEAD + lane] = al;
        }
        const float* hrow = h + (size_t)s * FG;
        ac0 += __shfl(al, h0) * hrow[f0];
        ac1 += __shfl(al, h1) * hrow[f1];
        ac2 += __shfl(al, h2) * hrow[f2];
        ac3 += __shfl(al, h3) * hrow[f3];
        ac4 += __shfl(al, h4) * hrow[f4];
        if (f5 < FG) ac5 += __shfl(al, h5) * hrow[f5];
    }
    float* orow = xg + (size_t)wid * FG;
    orow[f0] = fmaxf(ac0 + b_gat[f0], 0.f);
    orow[f1] = fmaxf(ac1 + b_gat[f1], 0.f);
    orow[f2] = fmaxf(ac2 + b_gat[f2], 0.f);
    orow[f3] = fmaxf(ac3 + b_gat[f3], 0.f);
    orow[f4] = fmaxf(ac4 + b_gat[f4], 0.f);
    if (f5 < FG) orow[f5] = fmaxf(ac5 + b_gat[f5], 0.f);
}

// ---------------- GCN aggregate: wave per node ----------------
__global__ __launch_bounds__(256) void k_gcn_agg(const float* __restrict__ h2,
                                                 const int* __restrict__ csr_src,
                                                 const int* __restrict__ offs, const int* __restrict__ deg,
                                                 const float* __restrict__ dinv, const float* __restrict__ b_gcn,
                                                 float* __restrict__ xg2) {
    int wid = (blockIdx.x * blockDim.x + threadIdx.x) >> 6;
    int lane = threadIdx.x & 63;
    if (wid >= NN) return;
    int o0 = offs[wid], d = deg[wid];
    float wv = dinv[wid];
    int f0 = lane, f1 = lane + 64, f2 = lane + 128, f3 = lane + 192, f4 = lane + 256, f5 = lane + 320;
    float ac0 = 0, ac1 = 0, ac2 = 0, ac3 = 0, ac4 = 0, ac5 = 0;
    for (int i = 0; i < d; i++) {
        int s = csr_src[o0 + i];
        float ws = dinv[s];
        const float* hrow = h2 + (size_t)s * FG;
        ac0 += ws * hrow[f0];
        ac1 += ws * hrow[f1];
        ac2 += ws * hrow[f2];
        ac3 += ws * hrow[f3];
        ac4 += ws * hrow[f4];
        if (f5 < FG) ac5 += ws * hrow[f5];
    }
    float* orow = xg2 + (size_t)wid * FG;
    orow[f0] = fmaxf(wv * ac0 + b_gcn[f0], 0.f);
    orow[f1] = fmaxf(wv * ac1 + b_gcn[f1], 0.f);
    orow[f2] = fmaxf(wv * ac2 + b_gcn[f2], 0.f);
    orow[f3] = fmaxf(wv * ac3 + b_gcn[f3], 0.f);
    orow[f4] = fmaxf(wv * ac4 + b_gcn[f4], 0.f);
    if (f5 < FG) orow[f5] = fmaxf(wv * ac5 + b_gcn[f5], 0.f);
}

// ---------------- per-graph max+mean pool ----------------
__device__ __forceinline__ int lowerB(const int* a, int n, int key) {
    int lo = 0, hi = n;
    while (lo < hi) { int mid = (lo + hi) >> 1; if (a[mid] < key) lo = mid + 1; else hi = mid; }
    return lo;
}

__global__ __launch_bounds__(384) void k_pool(const float* __restrict__ xg2, const int* __restrict__ batch,
                                              float* __restrict__ pooled) {
    int g = blockIdx.x;
    int f = threadIdx.x;
    int s = lowerB(batch, NN, g);
    int e = lowerB(batch, NN, g + 1);
    if (f >= FG) return;
    float mx = -INFINITY, sm = 0.f;
    for (int n = s; n < e; n++) {
        float v = xg2[(size_t)n * FG + f];
        mx = fmaxf(mx, v);
        sm += v;
    }
    int cnt = e - s;
    pooled[g * 700 + f] = mx;
    pooled[g * 700 + FG + f] = sm / fmaxf((float)cnt, 1.f);
}

// ---------------- protein conv branch ----------------
__global__ __launch_bounds__(256) void k_conv(const int* __restrict__ target, const float* __restrict__ emb,
                                              const float* __restrict__ Wc, const float* __restrict__ bc,
                                              float* __restrict__ xt) {
    int tid = blockIdx.x * 256 + threadIdx.x;
    if (tid >= BB * 560) return;
    int b = tid / 560;
    int r = tid % 560;
    int f = r / 35, t = r % 35;
    float acc = bc[f];
    const int* tg = target + b * LL;
    const float* wf = Wc + f * 1024;        // W_conv[f][e][k] = wf[e*8 + k]
    for (int k = 0; k < 8; k++) {
        const float* er = emb + tg[t + k] * 128;
        const float* wk = wf + k;
        #pragma unroll 16
        for (int e = 0; e < 128; e++) acc += er[e] * wk[e * 8];
    }
    xt[tid] = acc;
}

// ---------------- final dot + sigmoid ----------------
__global__ __launch_bounds__(256) void k_out(const float* __restrict__ f1, const float* __restrict__ W_out,
                                             const float* __restrict__ b_out, float* __restrict__ out) {
    int wid = (blockIdx.x * blockDim.x + threadIdx.x) >> 6;
    int lane = threadIdx.x & 63;
    if (wid >= BB) return;
    const float* xr = f1 + (size_t)wid * 512;
    float acc = 0.f;
    #pragma unroll
    for (int k = 0; k < 8; k++) acc += xr[lane + k * 64] * W_out[lane + k * 64];
    #pragma unroll
    for (int d = 32; d; d >>= 1) acc += __shfl_xor(acc, d);
    if (lane == 0) out[wid] = 1.f / (1.f + __expf(-(acc + b_out[0])));
}

// ---------------- host launcher ----------------
extern "C" void kernel_launch(void* const* d_in, const int* in_sizes, int n_in,
                              void* d_out, int out_size, void* d_ws, size_t ws_size,
                              hipStream_t stream) {
    const float* x      = (const float*)d_in[0];
    const int*   ei     = (const int*)d_in[1];
    const int*   batch  = (const int*)d_in[2];
    const int*   target = (const int*)d_in[3];
    const float* W_gat  = (const float*)d_in[4];
    const float* att_s  = (const float*)d_in[5];
    const float* att_d  = (const float*)d_in[6];
    const float* b_gat  = (const float*)d_in[7];
    const float* W_gcn  = (const float*)d_in[8];
    const float* b_gcn  = (const float*)d_in[9];
    const float* W_fcg1 = (const float*)d_in[10];
    const float* b_fcg1 = (const float*)d_in[11];
    const float* W_fcg2 = (const float*)d_in[12];
    const float* b_fcg2 = (const float*)d_in[13];
    const float* embxt  = (const float*)d_in[14];
    const float* W_conv = (const float*)d_in[15];
    const float* b_conv = (const float*)d_in[16];
    const float* W_fcxt = (const float*)d_in[17];
    const float* b_fcxt = (const float*)d_in[18];
    const float* W_fc1  = (const float*)d_in[19];
    const float* b_fc1  = (const float*)d_in[20];
    const float* W_out  = (const float*)d_in[21];
    const float* b_out  = (const float*)d_in[22];

    float* out_sig = (float*)d_out;           // [500]
    float* alphaOut = (float*)d_out + BB;     // [850000 * 10]

    // workspace carve (256B aligned)
    size_t o = 0;
    auto alloc = [&](size_t bytes) -> void* {
        o = (o + 255) & ~(size_t)255;
        void* p = (char*)d_ws + o;
        o += bytes;
        return p;
    };
    int*   deg     = (int*)alloc((size_t)NN * 4);
    int*   cur     = (int*)alloc((size_t)NN * 4);
    int*   offs    = (int*)alloc((size_t)NN * 4);
    int*   part    = (int*)alloc(128 * 4);
    int*   pscan   = (int*)alloc(128 * 4);
    int*   csr_src = (int*)alloc((size_t)ETOT * 4);
    int*   csr_eid = (int*)alloc((size_t)ETOT * 4);
    float* dinv    = (float*)alloc((size_t)NN * 4);
    float* a_s     = (float*)alloc((size_t)NN * NHEAD * 4);
    float* a_d     = (float*)alloc((size_t)NN * NHEAD * 4);
    float* bufA    = (float*)alloc((size_t)NN * FG * 4);   // h, then h2
    float* bufB    = (float*)alloc((size_t)NN * FG * 4);   // xg1, then xg2
    float* pooled  = (float*)alloc((size_t)BB * 700 * 4);
    float* t1      = (float*)alloc((size_t)BB * 1500 * 4);
    float* xt      = (float*)alloc((size_t)BB * 560 * 4);
    float* xc      = (float*)alloc((size_t)BB * 256 * 4);
    float* f1      = (float*)alloc((size_t)BB * 512 * 4);
    (void)ws_size; (void)n_in; (void)in_sizes; (void)out_size;

    auto gemm = [&](const float* A, const float* Bm, const float* bias, float* C,
                    int M, int N, int K, int ldc, int act) {
        dim3 g((N + 63) / 64, (M + 63) / 64);
        k_gemm<<<g, 256, 0, stream>>>(A, Bm, bias, C, M, N, K, ldc, act);
    };

    // graph prep
    k_init<<<(NN + 255) / 256, 256, 0, stream>>>(deg, cur);
    k_deg<<<(EE + 255) / 256, 256, 0, stream>>>(ei, deg);
    k_scan1<<<NCHUNK, 512, 0, stream>>>(deg, part);
    k_scan2<<<1, 64, 0, stream>>>(part, pscan);
    k_scan3<<<NCHUNK, 512, 0, stream>>>(deg, pscan, offs);
    k_scatter<<<(ETOT + 255) / 256, 256, 0, stream>>>(ei, offs, cur, csr_src, csr_eid);
    k_dinv<<<(NN + 255) / 256, 256, 0, stream>>>(deg, dinv);

    // GAT
    gemm(x, W_gat, nullptr, bufA, NN, FG, 35, FG, 0);                       // h
    k_att<<<(NN * NHEAD + 255) / 256, 256, 0, stream>>>(bufA, att_s, att_d, a_s, a_d);
    k_gat_agg<<<(NN + 3) / 4, 256, 0, stream>>>(bufA, a_s, a_d, csr_src, csr_eid,
                                                offs, deg, b_gat, bufB, alphaOut);  // xg1 + alpha

    // GCN
    gemm(bufB, W_gcn, nullptr, bufA, NN, FG, FG, FG, 0);                    // h2
    k_gcn_agg<<<(NN + 3) / 4, 256, 0, stream>>>(bufA, csr_src, offs, deg, dinv, b_gcn, bufB);  // xg2

    // pool + graph FC
    k_pool<<<BB, 384, 0, stream>>>(bufB, batch, pooled);
    gemm(pooled, W_fcg1, b_fcg1, t1, BB, 1500, 700, 1500, 1);
    gemm(t1, W_fcg2, b_fcg2, xc, BB, 128, 1500, 256, 0);                    // xc[:, :128]

    // protein branch
    k_conv<<<(BB * 560 + 255) / 256, 256, 0, stream>>>(target, embxt, W_conv, b_conv, xt);
    gemm(xt, W_fcxt, b_fcxt, xc + 128, BB, 128, 560, 256, 0);               // xc[:, 128:]

    // fusion
    gemm(xc, W_fc1, b_fc1, f1, BB, 512, 256, 512, 1);
    k_out<<<(BB + 3) / 4, 256, 0, stream>>>(f1, W_out, b_out, out_sig);
}

// Round 2
// 1592.628 us; speedup vs baseline: 1.2643x; 1.2643x over previous
//
#include <hip/hip_runtime.h>
#include <math.h>

#define NN 50000
#define EE 800000
#define BB 500
#define LL 42
#define NHEAD 10
#define FH 35
#define FG 350
#define ETOT (EE + NN)
#define NCHUNK ((NN + 511) / 512)

#define LDH 352          // f32 row stride for h / h2
#define KPAD 384         // bf16 K padding for GCN GEMM
#define MPAD 50048       // M padded to multiple of 128

typedef unsigned short ushort_t;
typedef __attribute__((ext_vector_type(8))) short short8v;
typedef __attribute__((ext_vector_type(4))) float float4v;

__device__ __forceinline__ float lrelu(float x) { return x > 0.f ? x : 0.2f * x; }

__device__ __forceinline__ ushort_t f2bf(float f) {
    unsigned int u = __float_as_uint(f);
    u += 0x7fffu + ((u >> 16) & 1u);      // round-to-nearest-even
    return (ushort_t)(u >> 16);
}

__device__ __forceinline__ void async_cp16(const void* g, void* l) {
    __builtin_amdgcn_global_load_lds((const __attribute__((address_space(1))) unsigned int*)g,
                                     (__attribute__((address_space(3))) unsigned int*)l, 16, 0, 0);
}

// ---------------- graph prep ----------------
__global__ __launch_bounds__(256) void k_init(int* deg, int* cur) {
    int i = blockIdx.x * 256 + threadIdx.x;
    if (i < NN) { deg[i] = 1; cur[i] = 0; }   // deg=1 accounts for the self-loop
}

__global__ __launch_bounds__(256) void k_deg(const int* __restrict__ ei, int* deg) {
    int i = blockIdx.x * 256 + threadIdx.x;
    if (i < EE) atomicAdd(&deg[ei[EE + i]], 1);
}

__global__ __launch_bounds__(512) void k_scan1(const int* __restrict__ deg, int* part) {
    int i = blockIdx.x * 512 + threadIdx.x;
    int lane = threadIdx.x & 63, wv = threadIdx.x >> 6;
    int x = (i < NN) ? deg[i] : 0;
    #pragma unroll
    for (int d = 32; d; d >>= 1) x += __shfl_xor(x, d);
    __shared__ int wsum[8];
    if (lane == 0) wsum[wv] = x;
    __syncthreads();
    if (threadIdx.x == 0) {
        int s = 0;
        #pragma unroll
        for (int w = 0; w < 8; w++) s += wsum[w];
        part[blockIdx.x] = s;
    }
}

__global__ __launch_bounds__(64) void k_scan2(const int* __restrict__ part, int* pscan) {
    int l = threadIdx.x;
    int v0 = (l < NCHUNK) ? part[l] : 0;
    #pragma unroll
    for (int d = 1; d < 64; d <<= 1) { int t = __shfl_up(v0, d); if (l >= d) v0 += t; }
    int tot0 = __shfl(v0, 63);
    int v1 = (64 + l < NCHUNK) ? part[64 + l] : 0;
    #pragma unroll
    for (int d = 1; d < 64; d <<= 1) { int t = __shfl_up(v1, d); if (l >= d) v1 += t; }
    v1 += tot0;
    if (l < NCHUNK) pscan[l] = v0;
    if (64 + l < NCHUNK) pscan[64 + l] = v1;
}

__global__ __launch_bounds__(512) void k_scan3(const int* __restrict__ deg, const int* __restrict__ pscan,
                                               int* offs) {
    int i = blockIdx.x * 512 + threadIdx.x;
    int lane = threadIdx.x & 63, wv = threadIdx.x >> 6;
    int x = (i < NN) ? deg[i] : 0;
    int incl = x;
    #pragma unroll
    for (int d = 1; d < 64; d <<= 1) { int t = __shfl_up(incl, d); if (lane >= d) incl += t; }
    __shared__ int wtot[8];
    if (lane == 63) wtot[wv] = incl;
    __syncthreads();
    int woff = 0;
    for (int w = 0; w < wv; w++) woff += wtot[w];
    int base = (blockIdx.x == 0) ? 0 : pscan[blockIdx.x - 1];
    if (i < NN) offs[i] = base + woff + incl - x;   // exclusive prefix
}

__global__ __launch_bounds__(256) void k_scatter(const int* __restrict__ ei, const int* __restrict__ offs,
                                                 int* cur, int* csr_src, int* csr_eid) {
    int i = blockIdx.x * 256 + threadIdx.x;
    if (i < EE) {
        int s = ei[i], d = ei[EE + i];
        int slot = atomicAdd(&cur[d], 1);
        int p = offs[d] + slot;
        csr_src[p] = s;
        csr_eid[p] = i;
    } else if (i < ETOT) {
        int v = i - EE;
        int slot = atomicAdd(&cur[v], 1);
        int p = offs[v] + slot;
        csr_src[p] = v;
        csr_eid[p] = i;   // self-loop edge id = EE + v
    }
}

__global__ __launch_bounds__(256) void k_dinv(const int* __restrict__ deg, float* dinv) {
    int i = blockIdx.x * 256 + threadIdx.x;
    if (i < NN) dinv[i] = rsqrtf((float)deg[i]);
}

// ---------------- W_gcn -> transposed, padded bf16: Wt[n][k] ----------------
__global__ __launch_bounds__(256) void k_prep_wgcn(const float* __restrict__ W, ushort_t* __restrict__ Wt) {
    int i = blockIdx.x * 256 + threadIdx.x;
    if (i >= KPAD * KPAD) return;
    int n = i / KPAD, k = i % KPAD;
    float v = (n < FG && k < FG) ? W[k * FG + n] : 0.f;
    Wt[i] = f2bf(v);
}

// ---------------- generic f32 tiled GEMM: C = act(A[M,K] @ B[K,N] + bias) ----------------
__global__ __launch_bounds__(256) void k_gemm(const float* __restrict__ A, const float* __restrict__ B,
                                              const float* __restrict__ bias, float* __restrict__ C,
                                              int M, int N, int K, int ldc, int act) {
    __shared__ float As[64][33];
    __shared__ __align__(16) float Bs[32][68];
    int tid = threadIdx.x;
    int tx = tid & 15, ty = tid >> 4;
    int m_base = blockIdx.y * 64, n_base = blockIdx.x * 64;
    float acc[4][4] = {};
    for (int k0 = 0; k0 < K; k0 += 32) {
        #pragma unroll
        for (int l = 0; l < 8; l++) {
            int idx = tid + l * 256;
            int i = idx >> 5, j = idx & 31;
            int gm = m_base + i, gk = k0 + j;
            As[i][j] = (gm < M && gk < K) ? A[(size_t)gm * K + gk] : 0.f;
        }
        #pragma unroll
        for (int l = 0; l < 8; l++) {
            int idx = tid + l * 256;
            int kk = idx >> 6, n = idx & 63;
            int gk = k0 + kk, gn = n_base + n;
            Bs[kk][n] = (gk < K && gn < N) ? B[(size_t)gk * N + gn] : 0.f;
        }
        __syncthreads();
        #pragma unroll
        for (int kk = 0; kk < 32; kk++) {
            float4 b4 = *(const float4*)&Bs[kk][tx * 4];
            float a0 = As[ty * 4 + 0][kk];
            float a1 = As[ty * 4 + 1][kk];
            float a2 = As[ty * 4 + 2][kk];
            float a3 = As[ty * 4 + 3][kk];
            acc[0][0] += a0 * b4.x; acc[0][1] += a0 * b4.y; acc[0][2] += a0 * b4.z; acc[0][3] += a0 * b4.w;
            acc[1][0] += a1 * b4.x; acc[1][1] += a1 * b4.y; acc[1][2] += a1 * b4.z; acc[1][3] += a1 * b4.w;
            acc[2][0] += a2 * b4.x; acc[2][1] += a2 * b4.y; acc[2][2] += a2 * b4.z; acc[2][3] += a2 * b4.w;
            acc[3][0] += a3 * b4.x; acc[3][1] += a3 * b4.y; acc[3][2] += a3 * b4.z; acc[3][3] += a3 * b4.w;
        }
        __syncthreads();
    }
    #pragma unroll
    for (int r = 0; r < 4; r++) {
        int m = m_base + ty * 4 + r;
        if (m >= M) continue;
        #pragma unroll
        for (int c = 0; c < 4; c++) {
            int n = n_base + tx * 4 + c;
            if (n >= N) continue;
            float v = acc[r][c];
            if (bias) v += bias[n];
            if (act) v = fmaxf(v, 0.f);
            C[(size_t)m * ldc + n] = v;
        }
    }
}

// ---------------- bf16 MFMA GEMM: C[M,Nv](f32,ldc) = A[Mpad,lda](bf16) @ Bt[Npad,lda](bf16,n-major) ----------------
// tile 128x64, BK=64, 4 waves in 2x2, wave tile 64x32 (4x2 fragments of 16x16x32)
__global__ __launch_bounds__(256) void k_mfma(const ushort_t* __restrict__ A, const ushort_t* __restrict__ Bt,
                                              float* __restrict__ C, int M, int Nv, int ldc, int lda,
                                              int ksteps) {
    __shared__ ushort_t As[128 * 64];
    __shared__ ushort_t Bs[64 * 64];
    int tid = threadIdx.x;
    int wid = tid >> 6, lane = tid & 63;
    int m0 = blockIdx.y * 128, n0 = blockIdx.x * 64;
    int wm0 = (wid >> 1) * 64, wn0 = (wid & 1) * 32;
    int srow = tid >> 3;              // staging: 8 lanes x 16B per row(128B)
    int scol = (tid & 7) * 8;
    float4v acc[4][2] = {{{0.f,0.f,0.f,0.f},{0.f,0.f,0.f,0.f}},
                         {{0.f,0.f,0.f,0.f},{0.f,0.f,0.f,0.f}},
                         {{0.f,0.f,0.f,0.f},{0.f,0.f,0.f,0.f}},
                         {{0.f,0.f,0.f,0.f},{0.f,0.f,0.f,0.f}}};
    // fragment read offsets (ushort units)
    int a_off = (wm0 + (lane & 15)) * 64 + (lane >> 4) * 8;
    int b_off = (wn0 + (lane & 15)) * 64 + (lane >> 4) * 8;
    for (int ks = 0; ks < ksteps; ks++) {
        int k0 = ks * 64;
        #pragma unroll
        for (int r = 0; r < 4; r++) {
            const ushort_t* g = A + (size_t)(m0 + r * 32 + srow) * lda + k0 + scol;
            async_cp16(g, As + (r * 256 + tid) * 8);
        }
        #pragma unroll
        for (int r = 0; r < 2; r++) {
            const ushort_t* g = Bt + (size_t)(n0 + r * 32 + srow) * lda + k0 + scol;
            async_cp16(g, Bs + (r * 256 + tid) * 8);
        }
        __syncthreads();
        #pragma unroll
        for (int kh = 0; kh < 2; kh++) {
            short8v b0 = *(const short8v*)&Bs[b_off + kh * 32];
            short8v b1 = *(const short8v*)&Bs[b_off + 16 * 64 + kh * 32];
            #pragma unroll
            for (int mi = 0; mi < 4; mi++) {
                short8v a = *(const short8v*)&As[a_off + mi * 16 * 64 + kh * 32];
                acc[mi][0] = __builtin_amdgcn_mfma_f32_16x16x32_bf16(a, b0, acc[mi][0], 0, 0, 0);
                acc[mi][1] = __builtin_amdgcn_mfma_f32_16x16x32_bf16(a, b1, acc[mi][1], 0, 0, 0);
            }
        }
        __syncthreads();
    }
    int lm = m0 + wm0 + (lane >> 4) * 4;
    int lc = n0 + wn0 + (lane & 15);
    #pragma unroll
    for (int mi = 0; mi < 4; mi++) {
        #pragma unroll
        for (int ni = 0; ni < 2; ni++) {
            int col = lc + ni * 16;
            if (col >= Nv) continue;
            #pragma unroll
            for (int r = 0; r < 4; r++) {
                int row = lm + mi * 16 + r;
                if (row < M) C[(size_t)row * ldc + col] = acc[mi][ni][r];
            }
        }
    }
}

// ---------------- GAT attention logits ----------------
__global__ __launch_bounds__(256) void k_att(const float* __restrict__ h, const float* __restrict__ att_s,
                                             const float* __restrict__ att_d, float* __restrict__ a_s,
                                             float* __restrict__ a_d) {
    int tid = blockIdx.x * 256 + threadIdx.x;
    if (tid >= NN * NHEAD) return;
    int n = tid / NHEAD, hd = tid % NHEAD;
    const float* hr = h + (size_t)n * LDH + hd * FH;
    const float* ws = att_s + hd * FH;
    const float* wd = att_d + hd * FH;
    float as = 0.f, ad = 0.f;
    #pragma unroll
    for (int c = 0; c < FH; c++) { float v = hr[c]; as += v * ws[c]; ad += v * wd[c]; }
    a_s[tid] = as;
    a_d[tid] = ad;
}

// ---------------- GAT aggregate: wave per node; writes bf16 xg1 (K padded to 384) ----------------
__global__ __launch_bounds__(256) void k_gat_agg(const float* __restrict__ h, const float* __restrict__ a_s,
                                                 const float* __restrict__ a_d,
                                                 const int* __restrict__ csr_src, const int* __restrict__ csr_eid,
                                                 const int* __restrict__ offs, const int* __restrict__ deg,
                                                 const float* __restrict__ b_gat,
                                                 ushort_t* __restrict__ xg1b, float* __restrict__ alphaOut) {
    int wid = (blockIdx.x * blockDim.x + threadIdx.x) >> 6;
    int lane = threadIdx.x & 63;
    if (wid >= NN) return;
    int o0 = offs[wid], d = deg[wid];
    bool mine = (lane < NHEAD);
    float adv = mine ? a_d[wid * NHEAD + lane] : 0.f;
    float m = -1e30f;
    for (int i = 0; i < d; i++) {
        int s = csr_src[o0 + i];
        if (mine) m = fmaxf(m, lrelu(a_s[s * NHEAD + lane] + adv));
    }
    float den = 0.f;
    for (int i = 0; i < d; i++) {
        int s = csr_src[o0 + i];
        if (mine) den += __expf(lrelu(a_s[s * NHEAD + lane] + adv) - m);
    }
    float rden = 1.f / (den + 1e-16f);
    int f0 = lane, f1 = lane + 64, f2 = lane + 128, f3 = lane + 192, f4 = lane + 256, f5 = lane + 320;
    int h0 = f0 / 35, h1 = f1 / 35, h2 = f2 / 35, h3 = f3 / 35, h4 = f4 / 35;
    int h5 = (f5 < FG) ? (f5 / 35) : 0;
    float ac0 = 0, ac1 = 0, ac2 = 0, ac3 = 0, ac4 = 0, ac5 = 0;
    for (int i = 0; i < d; i++) {
        int s = csr_src[o0 + i];
        int eid = csr_eid[o0 + i];
        float al = 0.f;
        if (mine) {
            float e = lrelu(a_s[s * NHEAD + lane] + adv);
            al = __expf(e - m) * rden;
            alphaOut[(size_t)eid * NHEAD + lane] = al;
        }
        const float* hrow = h + (size_t)s * LDH;
        ac0 += __shfl(al, h0) * hrow[f0];
        ac1 += __shfl(al, h1) * hrow[f1];
        ac2 += __shfl(al, h2) * hrow[f2];
        ac3 += __shfl(al, h3) * hrow[f3];
        ac4 += __shfl(al, h4) * hrow[f4];
        if (f5 < FG) ac5 += __shfl(al, h5) * hrow[f5];
    }
    ushort_t* orow = xg1b + (size_t)wid * KPAD;
    orow[f0] = f2bf(fmaxf(ac0 + b_gat[f0], 0.f));
    orow[f1] = f2bf(fmaxf(ac1 + b_gat[f1], 0.f));
    orow[f2] = f2bf(fmaxf(ac2 + b_gat[f2], 0.f));
    orow[f3] = f2bf(fmaxf(ac3 + b_gat[f3], 0.f));
    orow[f4] = f2bf(fmaxf(ac4 + b_gat[f4], 0.f));
    orow[f5] = (f5 < FG) ? f2bf(fmaxf(ac5 + b_gat[f5], 0.f)) : (ushort_t)0;
}

// zero pad rows 50000..50047 of xg1b so GEMM A-staging reads defined data
__global__ __launch_bounds__(256) void k_zero_tail(ushort_t* xg1b) {
    int i = blockIdx.x * 256 + threadIdx.x;
    int total = (MPAD - NN) * KPAD;
    if (i < total) xg1b[(size_t)NN * KPAD + i] = 0;
}

// ---------------- GCN aggregate: wave per node ----------------
__global__ __launch_bounds__(256) void k_gcn_agg(const float* __restrict__ h2,
                                                 const int* __restrict__ csr_src,
                                                 const int* __restrict__ offs, const int* __restrict__ deg,
                                                 const float* __restrict__ dinv, const float* __restrict__ b_gcn,
                                                 float* __restrict__ xg2) {
    int wid = (blockIdx.x * blockDim.x + threadIdx.x) >> 6;
    int lane = threadIdx.x & 63;
    if (wid >= NN) return;
    int o0 = offs[wid], d = deg[wid];
    float wv = dinv[wid];
    int f0 = lane, f1 = lane + 64, f2 = lane + 128, f3 = lane + 192, f4 = lane + 256, f5 = lane + 320;
    float ac0 = 0, ac1 = 0, ac2 = 0, ac3 = 0, ac4 = 0, ac5 = 0;
    for (int i = 0; i < d; i++) {
        int s = csr_src[o0 + i];
        float ws = dinv[s];
        const float* hrow = h2 + (size_t)s * LDH;
        ac0 += ws * hrow[f0];
        ac1 += ws * hrow[f1];
        ac2 += ws * hrow[f2];
        ac3 += ws * hrow[f3];
        ac4 += ws * hrow[f4];
        if (f5 < FG) ac5 += ws * hrow[f5];
    }
    float* orow = xg2 + (size_t)wid * FG;
    orow[f0] = fmaxf(wv * ac0 + b_gcn[f0], 0.f);
    orow[f1] = fmaxf(wv * ac1 + b_gcn[f1], 0.f);
    orow[f2] = fmaxf(wv * ac2 + b_gcn[f2], 0.f);
    orow[f3] = fmaxf(wv * ac3 + b_gcn[f3], 0.f);
    orow[f4] = fmaxf(wv * ac4 + b_gcn[f4], 0.f);
    if (f5 < FG) orow[f5] = fmaxf(wv * ac5 + b_gcn[f5], 0.f);
}

// ---------------- per-graph max+mean pool ----------------
__device__ __forceinline__ int lowerB(const int* a, int n, int key) {
    int lo = 0, hi = n;
    while (lo < hi) { int mid = (lo + hi) >> 1; if (a[mid] < key) lo = mid + 1; else hi = mid; }
    return lo;
}

__global__ __launch_bounds__(384) void k_pool(const float* __restrict__ xg2, const int* __restrict__ batch,
                                              float* __restrict__ pooled) {
    int g = blockIdx.x;
    int f = threadIdx.x;
    int s = lowerB(batch, NN, g);
    int e = lowerB(batch, NN, g + 1);
    if (f >= FG) return;
    float mx = -INFINITY, sm = 0.f;
    for (int n = s; n < e; n++) {
        float v = xg2[(size_t)n * FG + f];
        mx = fmaxf(mx, v);
        sm += v;
    }
    int cnt = e - s;
    pooled[g * 700 + f] = mx;
    pooled[g * 700 + FG + f] = sm / fmaxf((float)cnt, 1.f);
}

// ---------------- protein conv branch ----------------
__global__ __launch_bounds__(256) void k_conv(const int* __restrict__ target, const float* __restrict__ emb,
                                              const float* __restrict__ Wc, const float* __restrict__ bc,
                                              float* __restrict__ xt) {
    int tid = blockIdx.x * 256 + threadIdx.x;
    if (tid >= BB * 560) return;
    int b = tid / 560;
    int r = tid % 560;
    int f = r / 35, t = r % 35;
    float acc = bc[f];
    const int* tg = target + b * LL;
    const float* wf = Wc + f * 1024;
    for (int k = 0; k < 8; k++) {
        const float* er = emb + tg[t + k] * 128;
        const float* wk = wf + k;
        #pragma unroll 16
        for (int e = 0; e < 128; e++) acc += er[e] * wk[e * 8];
    }
    xt[tid] = acc;
}

// ---------------- final dot + sigmoid ----------------
__global__ __launch_bounds__(256) void k_out(const float* __restrict__ f1, const float* __restrict__ W_out,
                                             const float* __restrict__ b_out, float* __restrict__ out) {
    int wid = (blockIdx.x * blockDim.x + threadIdx.x) >> 6;
    int lane = threadIdx.x & 63;
    if (wid >= BB) return;
    const float* xr = f1 + (size_t)wid * 512;
    float acc = 0.f;
    #pragma unroll
    for (int k = 0; k < 8; k++) acc += xr[lane + k * 64] * W_out[lane + k * 64];
    #pragma unroll
    for (int d = 32; d; d >>= 1) acc += __shfl_xor(acc, d);
    if (lane == 0) out[wid] = 1.f / (1.f + __expf(-(acc + b_out[0])));
}

// ---------------- host launcher ----------------
extern "C" void kernel_launch(void* const* d_in, const int* in_sizes, int n_in,
                              void* d_out, int out_size, void* d_ws, size_t ws_size,
                              hipStream_t stream) {
    const float* x      = (const float*)d_in[0];
    const int*   ei     = (const int*)d_in[1];
    const int*   batch  = (const int*)d_in[2];
    const int*   target = (const int*)d_in[3];
    const float* W_gat  = (const float*)d_in[4];
    const float* att_s  = (const float*)d_in[5];
    const float* att_d  = (const float*)d_in[6];
    const float* b_gat  = (const float*)d_in[7];
    const float* W_gcn  = (const float*)d_in[8];
    const float* b_gcn  = (const float*)d_in[9];
    const float* W_fcg1 = (const float*)d_in[10];
    const float* b_fcg1 = (const float*)d_in[11];
    const float* W_fcg2 = (const float*)d_in[12];
    const float* b_fcg2 = (const float*)d_in[13];
    const float* embxt  = (const float*)d_in[14];
    const float* W_conv = (const float*)d_in[15];
    const float* b_conv = (const float*)d_in[16];
    const float* W_fcxt = (const float*)d_in[17];
    const float* b_fcxt = (const float*)d_in[18];
    const float* W_fc1  = (const float*)d_in[19];
    const float* b_fc1  = (const float*)d_in[20];
    const float* W_out  = (const float*)d_in[21];
    const float* b_out  = (const float*)d_in[22];

    float* out_sig  = (float*)d_out;          // [500]
    float* alphaOut = (float*)d_out + BB;     // [850000 * 10]

    size_t o = 0;
    auto alloc = [&](size_t bytes) -> void* {
        o = (o + 255) & ~(size_t)255;
        void* p = (char*)d_ws + o;
        o += bytes;
        return p;
    };
    int*   deg     = (int*)alloc((size_t)NN * 4);
    int*   cur     = (int*)alloc((size_t)NN * 4);
    int*   offs    = (int*)alloc((size_t)NN * 4);
    int*   part    = (int*)alloc(128 * 4);
    int*   pscan   = (int*)alloc(128 * 4);
    int*   csr_src = (int*)alloc((size_t)ETOT * 4);
    int*   csr_eid = (int*)alloc((size_t)ETOT * 4);
    float* dinv    = (float*)alloc((size_t)NN * 4);
    float* a_s     = (float*)alloc((size_t)NN * NHEAD * 4);
    float* a_d     = (float*)alloc((size_t)NN * NHEAD * 4);
    ushort_t* WtG  = (ushort_t*)alloc((size_t)KPAD * KPAD * 2);
    float* pooled  = (float*)alloc((size_t)BB * 700 * 4);
    float* bufH    = (float*)alloc((size_t)NN * LDH * 4);      // h, then h2 (70.4 MB)
    char*  R2      = (char*)alloc((size_t)70 * 1024 * 1024);   // aliased region
    ushort_t* xg1b = (ushort_t*)R2;                            // [MPAD][KPAD] bf16 (38.4 MB)
    float* xg2     = (float*)R2;                               // [NN][FG] f32 (70 MB), after xg1b dead
    float* t1      = (float*)(R2 + (size_t)48 * 1024 * 1024);  // [500][1500]
    float* xt      = t1 + (size_t)BB * 1500;
    float* xc      = xt + (size_t)BB * 560;
    float* f1      = xc + (size_t)BB * 256;
    (void)ws_size; (void)n_in; (void)in_sizes; (void)out_size;

    auto gemm = [&](const float* A, const float* Bm, const float* bias, float* C,
                    int M, int N, int K, int ldc, int act) {
        dim3 g((N + 63) / 64, (M + 63) / 64);
        k_gemm<<<g, 256, 0, stream>>>(A, Bm, bias, C, M, N, K, ldc, act);
    };

    // graph prep
    k_init<<<(NN + 255) / 256, 256, 0, stream>>>(deg, cur);
    k_deg<<<(EE + 255) / 256, 256, 0, stream>>>(ei, deg);
    k_scan1<<<NCHUNK, 512, 0, stream>>>(deg, part);
    k_scan2<<<1, 64, 0, stream>>>(part, pscan);
    k_scan3<<<NCHUNK, 512, 0, stream>>>(deg, pscan, offs);
    k_scatter<<<(ETOT + 255) / 256, 256, 0, stream>>>(ei, offs, cur, csr_src, csr_eid);
    k_dinv<<<(NN + 255) / 256, 256, 0, stream>>>(deg, dinv);
    k_prep_wgcn<<<(KPAD * KPAD + 255) / 256, 256, 0, stream>>>(W_gcn, WtG);
    k_zero_tail<<<((MPAD - NN) * KPAD + 255) / 256, 256, 0, stream>>>(xg1b);

    // GAT
    gemm(x, W_gat, nullptr, bufH, NN, FG, 35, LDH, 0);                      // h (f32, ld 352)
    k_att<<<(NN * NHEAD + 255) / 256, 256, 0, stream>>>(bufH, att_s, att_d, a_s, a_d);
    k_gat_agg<<<(NN + 3) / 4, 256, 0, stream>>>(bufH, a_s, a_d, csr_src, csr_eid,
                                                offs, deg, b_gat, xg1b, alphaOut);

    // GCN: h2 = xg1 @ W_gcn via bf16 MFMA (overwrites bufH)
    {
        dim3 g(6, (MPAD) / 128);
        k_mfma<<<g, 256, 0, stream>>>(xg1b, WtG, bufH, NN, FG, LDH, KPAD, KPAD / 64);
    }
    k_gcn_agg<<<(NN + 3) / 4, 256, 0, stream>>>(bufH, csr_src, offs, deg, dinv, b_gcn, xg2);

    // pool + FC stacks (k_conv after k_pool: xt aliases dead xg2 region)
    k_pool<<<BB, 384, 0, stream>>>(xg2, batch, pooled);
    gemm(pooled, W_fcg1, b_fcg1, t1, BB, 1500, 700, 1500, 1);
    gemm(t1, W_fcg2, b_fcg2, xc, BB, 128, 1500, 256, 0);
    k_conv<<<(BB * 560 + 255) / 256, 256, 0, stream>>>(target, embxt, W_conv, b_conv, xt);
    gemm(xt, W_fcxt, b_fcxt, xc + 128, BB, 128, 560, 256, 0);
    gemm(xc, W_fc1, b_fc1, f1, BB, 512, 256, 512, 1);
    k_out<<<(BB + 3) / 4, 256, 0, stream>>>(f1, W_out, b_out, out_sig);
}

// Round 3
// 1278.971 us; speedup vs baseline: 1.5744x; 1.2452x over previous
//
#include <hip/hip_runtime.h>
#include <math.h>

#define NN 50000
#define EE 800000
#define BB 500
#define LL 42
#define NHEAD 10
#define FH 35
#define FG 350
#define ETOT (EE + NN)
#define NCHUNK ((NN + 511) / 512)

#define KPAD 384         // bf16 row stride for h / xg1 / h2
#define MPAD 50048       // M padded to multiple of 128

typedef unsigned short ushort_t;
typedef __attribute__((ext_vector_type(8))) short short8v;
typedef __attribute__((ext_vector_type(4))) float float4v;

__device__ __forceinline__ float lrelu(float x) { return x > 0.f ? x : 0.2f * x; }

__device__ __forceinline__ ushort_t f2bf(float f) {
    unsigned int u = __float_as_uint(f);
    u += 0x7fffu + ((u >> 16) & 1u);      // round-to-nearest-even
    return (ushort_t)(u >> 16);
}
__device__ __forceinline__ float bflo(unsigned u) { return __uint_as_float(u << 16); }
__device__ __forceinline__ float bfhi(unsigned u) { return __uint_as_float(u & 0xffff0000u); }
__device__ __forceinline__ unsigned packbf(float a, float b) {
    return (unsigned)f2bf(a) | ((unsigned)f2bf(b) << 16);
}

__device__ __forceinline__ void async_cp16(const void* g, void* l) {
    __builtin_amdgcn_global_load_lds((const __attribute__((address_space(1))) unsigned int*)g,
                                     (__attribute__((address_space(3))) unsigned int*)l, 16, 0, 0);
}

// ---------------- graph prep ----------------
__global__ __launch_bounds__(256) void k_init(int* deg, int* cur) {
    int i = blockIdx.x * 256 + threadIdx.x;
    if (i < NN) { deg[i] = 1; cur[i] = 0; }   // deg=1 accounts for the self-loop
}

__global__ __launch_bounds__(256) void k_deg(const int* __restrict__ ei, int* deg) {
    int i = blockIdx.x * 256 + threadIdx.x;
    if (i < EE) atomicAdd(&deg[ei[EE + i]], 1);
}

__global__ __launch_bounds__(512) void k_scan1(const int* __restrict__ deg, int* part) {
    int i = blockIdx.x * 512 + threadIdx.x;
    int lane = threadIdx.x & 63, wv = threadIdx.x >> 6;
    int x = (i < NN) ? deg[i] : 0;
    #pragma unroll
    for (int d = 32; d; d >>= 1) x += __shfl_xor(x, d);
    __shared__ int wsum[8];
    if (lane == 0) wsum[wv] = x;
    __syncthreads();
    if (threadIdx.x == 0) {
        int s = 0;
        #pragma unroll
        for (int w = 0; w < 8; w++) s += wsum[w];
        part[blockIdx.x] = s;
    }
}

__global__ __launch_bounds__(64) void k_scan2(const int* __restrict__ part, int* pscan) {
    int l = threadIdx.x;
    int v0 = (l < NCHUNK) ? part[l] : 0;
    #pragma unroll
    for (int d = 1; d < 64; d <<= 1) { int t = __shfl_up(v0, d); if (l >= d) v0 += t; }
    int tot0 = __shfl(v0, 63);
    int v1 = (64 + l < NCHUNK) ? part[64 + l] : 0;
    #pragma unroll
    for (int d = 1; d < 64; d <<= 1) { int t = __shfl_up(v1, d); if (l >= d) v1 += t; }
    v1 += tot0;
    if (l < NCHUNK) pscan[l] = v0;
    if (64 + l < NCHUNK) pscan[64 + l] = v1;
}

__global__ __launch_bounds__(512) void k_scan3(const int* __restrict__ deg, const int* __restrict__ pscan,
                                               int* offs) {
    int i = blockIdx.x * 512 + threadIdx.x;
    int lane = threadIdx.x & 63, wv = threadIdx.x >> 6;
    int x = (i < NN) ? deg[i] : 0;
    int incl = x;
    #pragma unroll
    for (int d = 1; d < 64; d <<= 1) { int t = __shfl_up(incl, d); if (lane >= d) incl += t; }
    __shared__ int wtot[8];
    if (lane == 63) wtot[wv] = incl;
    __syncthreads();
    int woff = 0;
    for (int w = 0; w < wv; w++) woff += wtot[w];
    int base = (blockIdx.x == 0) ? 0 : pscan[blockIdx.x - 1];
    if (i < NN) offs[i] = base + woff + incl - x;   // exclusive prefix
}

__global__ __launch_bounds__(256) void k_scatter(const int* __restrict__ ei, const int* __restrict__ offs,
                                                 int* cur, int* csr_src) {
    int i = blockIdx.x * 256 + threadIdx.x;
    if (i < EE) {
        int s = ei[i], d = ei[EE + i];
        int slot = atomicAdd(&cur[d], 1);
        csr_src[offs[d] + slot] = s;
    } else if (i < ETOT) {
        int v = i - EE;
        int slot = atomicAdd(&cur[v], 1);
        csr_src[offs[v] + slot] = v;
    }
}

__global__ __launch_bounds__(256) void k_dinv(const int* __restrict__ deg, float* dinv) {
    int i = blockIdx.x * 256 + threadIdx.x;
    if (i < NN) dinv[i] = rsqrtf((float)deg[i]);
}

// ---------------- weight / input prep (f32 -> padded transposed bf16) ----------------
__global__ __launch_bounds__(256) void k_prep_x(const float* __restrict__ x, ushort_t* __restrict__ xb) {
    int i = blockIdx.x * 256 + threadIdx.x;
    if (i >= MPAD * 64) return;
    int r = i / 64, k = i % 64;
    float v = (r < NN && k < 35) ? x[r * 35 + k] : 0.f;
    xb[i] = f2bf(v);
}

__global__ __launch_bounds__(256) void k_prep_wgat(const float* __restrict__ W, ushort_t* __restrict__ Wt) {
    int i = blockIdx.x * 256 + threadIdx.x;
    if (i >= KPAD * 64) return;
    int n = i / 64, k = i % 64;
    float v = (n < FG && k < 35) ? W[k * FG + n] : 0.f;
    Wt[i] = f2bf(v);
}

__global__ __launch_bounds__(256) void k_prep_wgcn(const float* __restrict__ W, ushort_t* __restrict__ Wt) {
    int i = blockIdx.x * 256 + threadIdx.x;
    if (i >= KPAD * KPAD) return;
    int n = i / KPAD, k = i % KPAD;
    float v = (n < FG && k < FG) ? W[k * FG + n] : 0.f;
    Wt[i] = f2bf(v);
}

// zero pad rows 50000..50047 of xg1b so GEMM A-staging reads defined data
__global__ __launch_bounds__(256) void k_zero_tail(ushort_t* xg1b) {
    int i = blockIdx.x * 256 + threadIdx.x;
    int total = (MPAD - NN) * KPAD;
    if (i < total) xg1b[(size_t)NN * KPAD + i] = 0;
}

// ---------------- generic f32 tiled GEMM (small layers): C = act(A @ B + bias) ----------------
__global__ __launch_bounds__(256) void k_gemm(const float* __restrict__ A, const float* __restrict__ B,
                                              const float* __restrict__ bias, float* __restrict__ C,
                                              int M, int N, int K, int ldc, int act) {
    __shared__ float As[64][33];
    __shared__ __align__(16) float Bs[32][68];
    int tid = threadIdx.x;
    int tx = tid & 15, ty = tid >> 4;
    int m_base = blockIdx.y * 64, n_base = blockIdx.x * 64;
    float acc[4][4] = {};
    for (int k0 = 0; k0 < K; k0 += 32) {
        #pragma unroll
        for (int l = 0; l < 8; l++) {
            int idx = tid + l * 256;
            int i = idx >> 5, j = idx & 31;
            int gm = m_base + i, gk = k0 + j;
            As[i][j] = (gm < M && gk < K) ? A[(size_t)gm * K + gk] : 0.f;
        }
        #pragma unroll
        for (int l = 0; l < 8; l++) {
            int idx = tid + l * 256;
            int kk = idx >> 6, n = idx & 63;
            int gk = k0 + kk, gn = n_base + n;
            Bs[kk][n] = (gk < K && gn < N) ? B[(size_t)gk * N + gn] : 0.f;
        }
        __syncthreads();
        #pragma unroll
        for (int kk = 0; kk < 32; kk++) {
            float4 b4 = *(const float4*)&Bs[kk][tx * 4];
            float a0 = As[ty * 4 + 0][kk];
            float a1 = As[ty * 4 + 1][kk];
            float a2 = As[ty * 4 + 2][kk];
            float a3 = As[ty * 4 + 3][kk];
            acc[0][0] += a0 * b4.x; acc[0][1] += a0 * b4.y; acc[0][2] += a0 * b4.z; acc[0][3] += a0 * b4.w;
            acc[1][0] += a1 * b4.x; acc[1][1] += a1 * b4.y; acc[1][2] += a1 * b4.z; acc[1][3] += a1 * b4.w;
            acc[2][0] += a2 * b4.x; acc[2][1] += a2 * b4.y; acc[2][2] += a2 * b4.z; acc[2][3] += a2 * b4.w;
            acc[3][0] += a3 * b4.x; acc[3][1] += a3 * b4.y; acc[3][2] += a3 * b4.z; acc[3][3] += a3 * b4.w;
        }
        __syncthreads();
    }
    #pragma unroll
    for (int r = 0; r < 4; r++) {
        int m = m_base + ty * 4 + r;
        if (m >= M) continue;
        #pragma unroll
        for (int c = 0; c < 4; c++) {
            int n = n_base + tx * 4 + c;
            if (n >= N) continue;
            float v = acc[r][c];
            if (bias) v += bias[n];
            if (act) v = fmaxf(v, 0.f);
            C[(size_t)m * ldc + n] = v;
        }
    }
}

// ---------------- bf16 MFMA GEMM: C = A[Mpad,lda](bf16) @ Bt[Npad,lda](bf16,n-major) ----------------
// tile 128x64, BK=64, 4 waves in 2x2, wave tile 64x32 (4x2 fragments of 16x16x32)
__global__ __launch_bounds__(256) void k_mfma(const ushort_t* __restrict__ A, const ushort_t* __restrict__ Bt,
                                              void* __restrict__ C, int M, int Nv, int ldc, int lda,
                                              int ksteps, int bf16out) {
    __shared__ ushort_t As[128 * 64];
    __shared__ ushort_t Bs[64 * 64];
    int tid = threadIdx.x;
    int wid = tid >> 6, lane = tid & 63;
    int m0 = blockIdx.y * 128, n0 = blockIdx.x * 64;
    int wm0 = (wid >> 1) * 64, wn0 = (wid & 1) * 32;
    int srow = tid >> 3;              // staging: 8 lanes x 16B per row(128B)
    int scol = (tid & 7) * 8;
    float4v acc[4][2] = {{{0.f,0.f,0.f,0.f},{0.f,0.f,0.f,0.f}},
                         {{0.f,0.f,0.f,0.f},{0.f,0.f,0.f,0.f}},
                         {{0.f,0.f,0.f,0.f},{0.f,0.f,0.f,0.f}},
                         {{0.f,0.f,0.f,0.f},{0.f,0.f,0.f,0.f}}};
    int a_off = (wm0 + (lane & 15)) * 64 + (lane >> 4) * 8;
    int b_off = (wn0 + (lane & 15)) * 64 + (lane >> 4) * 8;
    for (int ks = 0; ks < ksteps; ks++) {
        int k0 = ks * 64;
        #pragma unroll
        for (int r = 0; r < 4; r++) {
            const ushort_t* g = A + (size_t)(m0 + r * 32 + srow) * lda + k0 + scol;
            async_cp16(g, As + (r * 256 + tid) * 8);
        }
        #pragma unroll
        for (int r = 0; r < 2; r++) {
            const ushort_t* g = Bt + (size_t)(n0 + r * 32 + srow) * lda + k0 + scol;
            async_cp16(g, Bs + (r * 256 + tid) * 8);
        }
        __syncthreads();
        #pragma unroll
        for (int kh = 0; kh < 2; kh++) {
            short8v b0 = *(const short8v*)&Bs[b_off + kh * 32];
            short8v b1 = *(const short8v*)&Bs[b_off + 16 * 64 + kh * 32];
            #pragma unroll
            for (int mi = 0; mi < 4; mi++) {
                short8v a = *(const short8v*)&As[a_off + mi * 16 * 64 + kh * 32];
                acc[mi][0] = __builtin_amdgcn_mfma_f32_16x16x32_bf16(a, b0, acc[mi][0], 0, 0, 0);
                acc[mi][1] = __builtin_amdgcn_mfma_f32_16x16x32_bf16(a, b1, acc[mi][1], 0, 0, 0);
            }
        }
        __syncthreads();
    }
    int lm = m0 + wm0 + (lane >> 4) * 4;
    int lc = n0 + wn0 + (lane & 15);
    #pragma unroll
    for (int mi = 0; mi < 4; mi++) {
        #pragma unroll
        for (int ni = 0; ni < 2; ni++) {
            int col = lc + ni * 16;
            if (col >= Nv) continue;
            #pragma unroll
            for (int r = 0; r < 4; r++) {
                int row = lm + mi * 16 + r;
                if (row >= M) continue;
                if (bf16out) ((ushort_t*)C)[(size_t)row * ldc + col] = f2bf(acc[mi][ni][r]);
                else         ((float*)C)[(size_t)row * ldc + col] = acc[mi][ni][r];
            }
        }
    }
}

// ---------------- GAT attention logits (bf16 h) ----------------
__global__ __launch_bounds__(256) void k_att(const ushort_t* __restrict__ hb, const float* __restrict__ att_s,
                                             const float* __restrict__ att_d, float* __restrict__ a_s,
                                             float* __restrict__ a_d) {
    int tid = blockIdx.x * 256 + threadIdx.x;
    if (tid >= NN * NHEAD) return;
    int n = tid / NHEAD, hd = tid % NHEAD;
    const ushort_t* hr = hb + (size_t)n * KPAD + hd * FH;
    const float* ws = att_s + hd * FH;
    const float* wd = att_d + hd * FH;
    float as = 0.f, ad = 0.f;
    #pragma unroll
    for (int c = 0; c < FH; c++) {
        float v = __uint_as_float(((unsigned)hr[c]) << 16);
        as += v * ws[c]; ad += v * wd[c];
    }
    a_s[tid] = as;
    a_d[tid] = ad;
}

// ---------------- GAT aggregate: wave per node, single pass, no max (softmax shift-invariant) ----------------
__global__ __launch_bounds__(256) void k_gat_agg(const ushort_t* __restrict__ hb, const float* __restrict__ a_s,
                                                 const float* __restrict__ a_d,
                                                 const int* __restrict__ csr_src,
                                                 const int* __restrict__ offs, const int* __restrict__ deg,
                                                 const float* __restrict__ b_gat,
                                                 ushort_t* __restrict__ xg1b, float* __restrict__ denArr) {
    int wid = (blockIdx.x * blockDim.x + threadIdx.x) >> 6;
    int lane = threadIdx.x & 63;
    if (wid >= NN) return;
    int o0 = offs[wid], d = deg[wid];
    bool mine = (lane < NHEAD);
    float adv = mine ? a_d[wid * NHEAD + lane] : 0.f;
    int hA0 = (2 * lane) / 35,       hA1 = (2 * lane + 1) / 35;
    int hB0 = (128 + 2 * lane) / 35, hB1 = (129 + 2 * lane) / 35;
    int hC0 = (256 + 2 * lane) / 35, hC1 = (257 + 2 * lane) / 35;   // ==10 for pad cols (h=0 there)
    float den = 0.f;
    float aL0 = 0.f, aH0 = 0.f, aL1 = 0.f, aH1 = 0.f, aL2 = 0.f, aH2 = 0.f;
    const unsigned* hb32 = (const unsigned*)hb;
    for (int i = 0; i < d; i++) {
        int s = csr_src[o0 + i];
        float asv = mine ? a_s[s * NHEAD + lane] : 0.f;
        float ex = __expf(lrelu(asv + adv));    // lanes>=10: exp(0)=1, only multiplies h-pad zeros
        den += ex;
        const unsigned* hr = hb32 + (size_t)s * (KPAD / 2);
        unsigned u0 = hr[lane], u1 = hr[lane + 64], u2 = hr[lane + 128];
        aL0 += __shfl(ex, hA0) * bflo(u0);  aH0 += __shfl(ex, hA1) * bfhi(u0);
        aL1 += __shfl(ex, hB0) * bflo(u1);  aH1 += __shfl(ex, hB1) * bfhi(u1);
        aL2 += __shfl(ex, hC0) * bflo(u2);  aH2 += __shfl(ex, hC1) * bfhi(u2);
    }
    float rden = 1.f / (den + 1e-16f);
    if (mine) denArr[wid * NHEAD + lane] = den;
    unsigned* orow = (unsigned*)(xg1b + (size_t)wid * KPAD);
    {
        int f = 2 * lane;
        float v0 = fmaxf(aL0 * __shfl(rden, hA0) + b_gat[f], 0.f);
        float v1 = fmaxf(aH0 * __shfl(rden, hA1) + b_gat[f + 1], 0.f);
        orow[lane] = packbf(v0, v1);
    }
    {
        int f = 128 + 2 * lane;
        float v0 = fmaxf(aL1 * __shfl(rden, hB0) + b_gat[f], 0.f);
        float v1 = fmaxf(aH1 * __shfl(rden, hB1) + b_gat[f + 1], 0.f);
        orow[lane + 64] = packbf(v0, v1);
    }
    {
        int f = 256 + 2 * lane;
        unsigned pv = 0;
        if (f < FG) {
            float v0 = fmaxf(aL2 * __shfl(rden, hC0) + b_gat[f], 0.f);
            float v1 = fmaxf(aH2 * __shfl(rden, hC1) + b_gat[f + 1], 0.f);
            pv = packbf(v0, v1);
        }
        orow[lane + 128] = pv;
    }
}

// ---------------- alpha in original edge order (coalesced writes; a_s/a_d/den are L2-resident) ----------------
__global__ __launch_bounds__(256) void k_alpha(const int* __restrict__ ei, const float* __restrict__ a_s,
                                               const float* __restrict__ a_d, const float* __restrict__ den,
                                               float* __restrict__ alphaOut) {
    int i = blockIdx.x * 256 + threadIdx.x;
    if (i >= ETOT * NHEAD) return;
    int e = i / NHEAD, hd = i % NHEAD;
    int s, dst;
    if (e < EE) { s = ei[e]; dst = ei[EE + e]; }
    else { s = dst = e - EE; }
    float ex = __expf(lrelu(a_s[s * NHEAD + hd] + a_d[dst * NHEAD + hd]));
    alphaOut[i] = ex / (den[dst * NHEAD + hd] + 1e-16f);
}

// ---------------- GCN aggregate: wave per node (bf16 h2 gathers) ----------------
__global__ __launch_bounds__(256) void k_gcn_agg(const ushort_t* __restrict__ h2b,
                                                 const int* __restrict__ csr_src,
                                                 const int* __restrict__ offs, const int* __restrict__ deg,
                                                 const float* __restrict__ dinv, const float* __restrict__ b_gcn,
                                                 float* __restrict__ xg2) {
    int wid = (blockIdx.x * blockDim.x + threadIdx.x) >> 6;
    int lane = threadIdx.x & 63;
    if (wid >= NN) return;
    int o0 = offs[wid], d = deg[wid];
    float wv = dinv[wid];
    float aL0 = 0.f, aH0 = 0.f, aL1 = 0.f, aH1 = 0.f, aL2 = 0.f, aH2 = 0.f;
    const unsigned* h32 = (const unsigned*)h2b;
    for (int i = 0; i < d; i++) {
        int s = csr_src[o0 + i];
        float ws = dinv[s];
        const unsigned* hr = h32 + (size_t)s * (KPAD / 2);
        unsigned u0 = hr[lane], u1 = hr[lane + 64], u2 = hr[lane + 128];
        aL0 += ws * bflo(u0);  aH0 += ws * bfhi(u0);
        aL1 += ws * bflo(u1);  aH1 += ws * bfhi(u1);
        aL2 += ws * bflo(u2);  aH2 += ws * bfhi(u2);
    }
    float* orow = xg2 + (size_t)wid * FG;
    {
        int f = 2 * lane;
        float2 v = { fmaxf(wv * aL0 + b_gcn[f], 0.f), fmaxf(wv * aH0 + b_gcn[f + 1], 0.f) };
        *(float2*)&orow[f] = v;
    }
    {
        int f = 128 + 2 * lane;
        float2 v = { fmaxf(wv * aL1 + b_gcn[f], 0.f), fmaxf(wv * aH1 + b_gcn[f + 1], 0.f) };
        *(float2*)&orow[f] = v;
    }
    {
        int f = 256 + 2 * lane;
        if (f < FG) {
            float2 v = { fmaxf(wv * aL2 + b_gcn[f], 0.f), fmaxf(wv * aH2 + b_gcn[f + 1], 0.f) };
            *(float2*)&orow[f] = v;
        }
    }
}

// ---------------- per-graph max+mean pool ----------------
__device__ __forceinline__ int lowerB(const int* a, int n, int key) {
    int lo = 0, hi = n;
    while (lo < hi) { int mid = (lo + hi) >> 1; if (a[mid] < key) lo = mid + 1; else hi = mid; }
    return lo;
}

__global__ __launch_bounds__(384) void k_pool(const float* __restrict__ xg2, const int* __restrict__ batch,
                                              float* __restrict__ pooled) {
    int g = blockIdx.x;
    int f = threadIdx.x;
    int s = lowerB(batch, NN, g);
    int e = lowerB(batch, NN, g + 1);
    if (f >= FG) return;
    float mx = -INFINITY, sm = 0.f;
    for (int n = s; n < e; n++) {
        float v = xg2[(size_t)n * FG + f];
        mx = fmaxf(mx, v);
        sm += v;
    }
    int cnt = e - s;
    pooled[g * 700 + f] = mx;
    pooled[g * 700 + FG + f] = sm / fmaxf((float)cnt, 1.f);
}

// ---------------- protein conv branch ----------------
__global__ __launch_bounds__(256) void k_conv(const int* __restrict__ target, const float* __restrict__ emb,
                                              const float* __restrict__ Wc, const float* __restrict__ bc,
                                              float* __restrict__ xt) {
    int tid = blockIdx.x * 256 + threadIdx.x;
    if (tid >= BB * 560) return;
    int b = tid / 560;
    int r = tid % 560;
    int f = r / 35, t = r % 35;
    float acc = bc[f];
    const int* tg = target + b * LL;
    const float* wf = Wc + f * 1024;
    for (int k = 0; k < 8; k++) {
        const float* er = emb + tg[t + k] * 128;
        const float* wk = wf + k;
        #pragma unroll 16
        for (int e = 0; e < 128; e++) acc += er[e] * wk[e * 8];
    }
    xt[tid] = acc;
}

// ---------------- final dot + sigmoid ----------------
__global__ __launch_bounds__(256) void k_out(const float* __restrict__ f1, const float* __restrict__ W_out,
                                             const float* __restrict__ b_out, float* __restrict__ out) {
    int wid = (blockIdx.x * blockDim.x + threadIdx.x) >> 6;
    int lane = threadIdx.x & 63;
    if (wid >= BB) return;
    const float* xr = f1 + (size_t)wid * 512;
    float acc = 0.f;
    #pragma unroll
    for (int k = 0; k < 8; k++) acc += xr[lane + k * 64] * W_out[lane + k * 64];
    #pragma unroll
    for (int d = 32; d; d >>= 1) acc += __shfl_xor(acc, d);
    if (lane == 0) out[wid] = 1.f / (1.f + __expf(-(acc + b_out[0])));
}

// ---------------- host launcher ----------------
extern "C" void kernel_launch(void* const* d_in, const int* in_sizes, int n_in,
                              void* d_out, int out_size, void* d_ws, size_t ws_size,
                              hipStream_t stream) {
    const float* x      = (const float*)d_in[0];
    const int*   ei     = (const int*)d_in[1];
    const int*   batch  = (const int*)d_in[2];
    const int*   target = (const int*)d_in[3];
    const float* W_gat  = (const float*)d_in[4];
    const float* att_s  = (const float*)d_in[5];
    const float* att_d  = (const float*)d_in[6];
    const float* b_gat  = (const float*)d_in[7];
    const float* W_gcn  = (const float*)d_in[8];
    const float* b_gcn  = (const float*)d_in[9];
    const float* W_fcg1 = (const float*)d_in[10];
    const float* b_fcg1 = (const float*)d_in[11];
    const float* W_fcg2 = (const float*)d_in[12];
    const float* b_fcg2 = (const float*)d_in[13];
    const float* embxt  = (const float*)d_in[14];
    const float* W_conv = (const float*)d_in[15];
    const float* b_conv = (const float*)d_in[16];
    const float* W_fcxt = (const float*)d_in[17];
    const float* b_fcxt = (const float*)d_in[18];
    const float* W_fc1  = (const float*)d_in[19];
    const float* b_fc1  = (const float*)d_in[20];
    const float* W_out  = (const float*)d_in[21];
    const float* b_out  = (const float*)d_in[22];

    float* out_sig  = (float*)d_out;          // [500]
    float* alphaOut = (float*)d_out + BB;     // [850000 * 10]

    size_t o = 0;
    auto alloc = [&](size_t bytes) -> void* {
        o = (o + 255) & ~(size_t)255;
        void* p = (char*)d_ws + o;
        o += bytes;
        return p;
    };
    int*   deg     = (int*)alloc((size_t)NN * 4);
    int*   cur     = (int*)alloc((size_t)NN * 4);
    int*   offs    = (int*)alloc((size_t)NN * 4);
    int*   part    = (int*)alloc(128 * 4);
    int*   pscan   = (int*)alloc(128 * 4);
    int*   csr_src = (int*)alloc((size_t)ETOT * 4);
    float* dinv    = (float*)alloc((size_t)NN * 4);
    float* a_s     = (float*)alloc((size_t)NN * NHEAD * 4);
    float* a_d     = (float*)alloc((size_t)NN * NHEAD * 4);
    float* denArr  = (float*)alloc((size_t)NN * NHEAD * 4);
    ushort_t* xb16 = (ushort_t*)alloc((size_t)MPAD * 64 * 2);
    ushort_t* WtGA = (ushort_t*)alloc((size_t)KPAD * 64 * 2);
    ushort_t* WtGC = (ushort_t*)alloc((size_t)KPAD * KPAD * 2);
    float* pooled  = (float*)alloc((size_t)BB * 700 * 4);
    ushort_t* hb   = (ushort_t*)alloc((size_t)MPAD * KPAD * 2);   // h (GAT), later h2 (GCN out)
    char*  R2      = (char*)alloc((size_t)NN * FG * 4);           // 70 MB aliased region
    ushort_t* xg1b = (ushort_t*)R2;                               // [MPAD][KPAD] bf16 (38.4 MB)
    float* xg2     = (float*)R2;                                  // [NN][FG] f32, after xg1b dead
    float* t1      = (float*)alloc((size_t)BB * 1500 * 4);
    float* xt      = (float*)alloc((size_t)BB * 560 * 4);
    float* xc      = (float*)alloc((size_t)BB * 256 * 4);
    float* f1      = (float*)alloc((size_t)BB * 512 * 4);
    (void)ws_size; (void)n_in; (void)in_sizes; (void)out_size;

    auto gemm = [&](const float* A, const float* Bm, const float* bias, float* C,
                    int M, int N, int K, int ldc, int act) {
        dim3 g((N + 63) / 64, (M + 63) / 64);
        k_gemm<<<g, 256, 0, stream>>>(A, Bm, bias, C, M, N, K, ldc, act);
    };

    // graph prep
    k_init<<<(NN + 255) / 256, 256, 0, stream>>>(deg, cur);
    k_deg<<<(EE + 255) / 256, 256, 0, stream>>>(ei, deg);
    k_scan1<<<NCHUNK, 512, 0, stream>>>(deg, part);
    k_scan2<<<1, 64, 0, stream>>>(part, pscan);
    k_scan3<<<NCHUNK, 512, 0, stream>>>(deg, pscan, offs);
    k_scatter<<<(ETOT + 255) / 256, 256, 0, stream>>>(ei, offs, cur, csr_src);
    k_dinv<<<(NN + 255) / 256, 256, 0, stream>>>(deg, dinv);

    // bf16 prep
    k_prep_x<<<(MPAD * 64 + 255) / 256, 256, 0, stream>>>(x, xb16);
    k_prep_wgat<<<(KPAD * 64 + 255) / 256, 256, 0, stream>>>(W_gat, WtGA);
    k_prep_wgcn<<<(KPAD * KPAD + 255) / 256, 256, 0, stream>>>(W_gcn, WtGC);
    k_zero_tail<<<((MPAD - NN) * KPAD + 255) / 256, 256, 0, stream>>>(xg1b);

    // GAT: h = x @ W_gat  (bf16 MFMA, bf16 out)
    {
        dim3 g(KPAD / 64, MPAD / 128);
        k_mfma<<<g, 256, 0, stream>>>(xb16, WtGA, hb, MPAD, KPAD, KPAD, 64, 1, 1);
    }
    k_att<<<(NN * NHEAD + 255) / 256, 256, 0, stream>>>(hb, att_s, att_d, a_s, a_d);
    k_gat_agg<<<(NN + 3) / 4, 256, 0, stream>>>(hb, a_s, a_d, csr_src, offs, deg, b_gat, xg1b, denArr);
    k_alpha<<<(ETOT * NHEAD + 255) / 256, 256, 0, stream>>>(ei, a_s, a_d, denArr, alphaOut);

    // GCN: h2 = xg1 @ W_gcn (bf16 MFMA, bf16 out, overwrites hb region)
    {
        dim3 g(KPAD / 64, MPAD / 128);
        k_mfma<<<g, 256, 0, stream>>>(xg1b, WtGC, hb, MPAD, KPAD, KPAD, KPAD, KPAD / 64, 1);
    }
    k_gcn_agg<<<(NN + 3) / 4, 256, 0, stream>>>(hb, csr_src, offs, deg, dinv, b_gcn, xg2);

    // pool + FC stacks
    k_pool<<<BB, 384, 0, stream>>>(xg2, batch, pooled);
    gemm(pooled, W_fcg1, b_fcg1, t1, BB, 1500, 700, 1500, 1);
    gemm(t1, W_fcg2, b_fcg2, xc, BB, 128, 1500, 256, 0);
    k_conv<<<(BB * 560 + 255) / 256, 256, 0, stream>>>(target, embxt, W_conv, b_conv, xt);
    gemm(xt, W_fcxt, b_fcxt, xc + 128, BB, 128, 560, 256, 0);
    gemm(xc, W_fc1, b_fc1, f1, BB, 512, 256, 512, 1);
    k_out<<<(BB + 3) / 4, 256, 0, stream>>>(f1, W_out, b_out, out_sig);
}

// Round 4
// 997.319 us; speedup vs baseline: 2.0190x; 1.2824x over previous
//
#include <hip/hip_runtime.h>
#include <math.h>

#define NN 50000
#define EE 800000
#define BB 500
#define LL 42
#define NHEAD 10
#define FH 35
#define FG 350
#define ETOT (EE + NN)
#define NCHUNK ((NN + 511) / 512)

#define KPAD 384         // bf16 row stride for h / xg1 / h2
#define MPAD 50048       // M padded to multiple of 128

typedef unsigned short ushort_t;
typedef __attribute__((ext_vector_type(8))) short short8v;
typedef __attribute__((ext_vector_type(4))) float float4v;

__device__ __forceinline__ float lrelu(float x) { return x > 0.f ? x : 0.2f * x; }

__device__ __forceinline__ ushort_t f2bf(float f) {
    unsigned int u = __float_as_uint(f);
    u += 0x7fffu + ((u >> 16) & 1u);      // round-to-nearest-even
    return (ushort_t)(u >> 16);
}
__device__ __forceinline__ float bflo(unsigned u) { return __uint_as_float(u << 16); }
__device__ __forceinline__ float bfhi(unsigned u) { return __uint_as_float(u & 0xffff0000u); }
__device__ __forceinline__ unsigned packbf(float a, float b) {
    return (unsigned)f2bf(a) | ((unsigned)f2bf(b) << 16);
}

__device__ __forceinline__ void async_cp16(const void* g, void* l) {
    __builtin_amdgcn_global_load_lds((const __attribute__((address_space(1))) unsigned int*)g,
                                     (__attribute__((address_space(3))) unsigned int*)l, 16, 0, 0);
}

// ---------------- graph prep ----------------
__global__ __launch_bounds__(256) void k_init(int* deg, int* cur) {
    int i = blockIdx.x * 256 + threadIdx.x;
    if (i < NN) { deg[i] = 1; cur[i] = 0; }   // deg=1 accounts for the self-loop
}

__global__ __launch_bounds__(256) void k_deg(const int* __restrict__ ei, int* deg) {
    int i = blockIdx.x * 256 + threadIdx.x;
    if (i < EE) atomicAdd(&deg[ei[EE + i]], 1);
}

__global__ __launch_bounds__(512) void k_scan1(const int* __restrict__ deg, int* part) {
    int i = blockIdx.x * 512 + threadIdx.x;
    int lane = threadIdx.x & 63, wv = threadIdx.x >> 6;
    int x = (i < NN) ? deg[i] : 0;
    #pragma unroll
    for (int d = 32; d; d >>= 1) x += __shfl_xor(x, d);
    __shared__ int wsum[8];
    if (lane == 0) wsum[wv] = x;
    __syncthreads();
    if (threadIdx.x == 0) {
        int s = 0;
        #pragma unroll
        for (int w = 0; w < 8; w++) s += wsum[w];
        part[blockIdx.x] = s;
    }
}

__global__ __launch_bounds__(64) void k_scan2(const int* __restrict__ part, int* pscan) {
    int l = threadIdx.x;
    int v0 = (l < NCHUNK) ? part[l] : 0;
    #pragma unroll
    for (int d = 1; d < 64; d <<= 1) { int t = __shfl_up(v0, d); if (l >= d) v0 += t; }
    int tot0 = __shfl(v0, 63);
    int v1 = (64 + l < NCHUNK) ? part[64 + l] : 0;
    #pragma unroll
    for (int d = 1; d < 64; d <<= 1) { int t = __shfl_up(v1, d); if (l >= d) v1 += t; }
    v1 += tot0;
    if (l < NCHUNK) pscan[l] = v0;
    if (64 + l < NCHUNK) pscan[64 + l] = v1;
}

__global__ __launch_bounds__(512) void k_scan3(const int* __restrict__ deg, const int* __restrict__ pscan,
                                               int* offs) {
    int i = blockIdx.x * 512 + threadIdx.x;
    int lane = threadIdx.x & 63, wv = threadIdx.x >> 6;
    int x = (i < NN) ? deg[i] : 0;
    int incl = x;
    #pragma unroll
    for (int d = 1; d < 64; d <<= 1) { int t = __shfl_up(incl, d); if (lane >= d) incl += t; }
    __shared__ int wtot[8];
    if (lane == 63) wtot[wv] = incl;
    __syncthreads();
    int woff = 0;
    for (int w = 0; w < wv; w++) woff += wtot[w];
    int base = (blockIdx.x == 0) ? 0 : pscan[blockIdx.x - 1];
    if (i < NN) offs[i] = base + woff + incl - x;   // exclusive prefix
}

__global__ __launch_bounds__(256) void k_scatter(const int* __restrict__ ei, const int* __restrict__ offs,
                                                 int* cur, int* csr_src) {
    int i = blockIdx.x * 256 + threadIdx.x;
    if (i < EE) {
        int s = ei[i], d = ei[EE + i];
        int slot = atomicAdd(&cur[d], 1);
        csr_src[offs[d] + slot] = s;
    } else if (i < ETOT) {
        int v = i - EE;
        int slot = atomicAdd(&cur[v], 1);
        csr_src[offs[v] + slot] = v;
    }
}

__global__ __launch_bounds__(256) void k_dinv(const int* __restrict__ deg, float* dinv) {
    int i = blockIdx.x * 256 + threadIdx.x;
    if (i < NN) dinv[i] = rsqrtf((float)deg[i]);
}

// ---------------- weight / input prep (f32 -> padded transposed bf16) ----------------
__global__ __launch_bounds__(256) void k_prep_x(const float* __restrict__ x, ushort_t* __restrict__ xb) {
    int i = blockIdx.x * 256 + threadIdx.x;
    if (i >= MPAD * 64) return;
    int r = i / 64, k = i % 64;
    float v = (r < NN && k < 35) ? x[r * 35 + k] : 0.f;
    xb[i] = f2bf(v);
}

__global__ __launch_bounds__(256) void k_prep_wgat(const float* __restrict__ W, ushort_t* __restrict__ Wt) {
    int i = blockIdx.x * 256 + threadIdx.x;
    if (i >= KPAD * 64) return;
    int n = i / 64, k = i % 64;
    float v = (n < FG && k < 35) ? W[k * FG + n] : 0.f;
    Wt[i] = f2bf(v);
}

__global__ __launch_bounds__(256) void k_prep_wgcn(const float* __restrict__ W, ushort_t* __restrict__ Wt) {
    int i = blockIdx.x * 256 + threadIdx.x;
    if (i >= KPAD * KPAD) return;
    int n = i / KPAD, k = i % KPAD;
    float v = (n < FG && k < FG) ? W[k * FG + n] : 0.f;
    Wt[i] = f2bf(v);
}

// zero pad rows 50000..50047 of xg1b so GEMM A-staging reads defined data
__global__ __launch_bounds__(256) void k_zero_tail(ushort_t* xg1b) {
    int i = blockIdx.x * 256 + threadIdx.x;
    int total = (MPAD - NN) * KPAD;
    if (i < total) xg1b[(size_t)NN * KPAD + i] = 0;
}

// ---------------- latency-oriented FC: row-per-wave, 64-col tiles, K unroll x8 ----------------
// C[m*ldc+col] = act(sum_k A[m*K+k]*B[k*N+col] + bias[col])
__global__ __launch_bounds__(256) void k_fc(const float* __restrict__ A, const float* __restrict__ B,
                                            const float* __restrict__ bias, float* __restrict__ C,
                                            int M, int N, int K, int ldc, int act) {
    int gw = (blockIdx.x * 256 + threadIdx.x) >> 6;
    int lane = threadIdx.x & 63;
    int ntiles = (N + 63) >> 6;
    int m = gw / ntiles, ct = gw % ntiles;
    if (m >= M) return;
    int col = ct * 64 + lane;
    bool ok = col < N;
    int colc = ok ? col : (N - 1);            // clamp for safe loads
    const float* Ar = A + (size_t)m * K;
    const float* Bc = B + colc;
    float acc = 0.f;
    int k = 0;
    for (; k + 8 <= K; k += 8) {
        float4 a0 = *(const float4*)&Ar[k];
        float4 a1 = *(const float4*)&Ar[k + 4];
        float b0 = Bc[(size_t)(k + 0) * N];
        float b1 = Bc[(size_t)(k + 1) * N];
        float b2 = Bc[(size_t)(k + 2) * N];
        float b3 = Bc[(size_t)(k + 3) * N];
        float b4 = Bc[(size_t)(k + 4) * N];
        float b5 = Bc[(size_t)(k + 5) * N];
        float b6 = Bc[(size_t)(k + 6) * N];
        float b7 = Bc[(size_t)(k + 7) * N];
        acc += a0.x * b0 + a0.y * b1 + a0.z * b2 + a0.w * b3;
        acc += a1.x * b4 + a1.y * b5 + a1.z * b6 + a1.w * b7;
    }
    for (; k < K; k++) acc += Ar[k] * Bc[(size_t)k * N];
    if (ok) {
        float v = acc + bias[col];
        if (act) v = fmaxf(v, 0.f);
        C[(size_t)m * ldc + col] = v;
    }
}

// ---------------- bf16 MFMA GEMM: C = A[Mpad,lda](bf16) @ Bt[Npad,lda](bf16,n-major) ----------------
// tile 128x64, BK=64, 4 waves in 2x2, wave tile 64x32 (4x2 fragments of 16x16x32)
__global__ __launch_bounds__(256) void k_mfma(const ushort_t* __restrict__ A, const ushort_t* __restrict__ Bt,
                                              void* __restrict__ C, int M, int Nv, int ldc, int lda,
                                              int ksteps, int bf16out) {
    __shared__ ushort_t As[128 * 64];
    __shared__ ushort_t Bs[64 * 64];
    int tid = threadIdx.x;
    int wid = tid >> 6, lane = tid & 63;
    int m0 = blockIdx.y * 128, n0 = blockIdx.x * 64;
    int wm0 = (wid >> 1) * 64, wn0 = (wid & 1) * 32;
    int srow = tid >> 3;              // staging: 8 lanes x 16B per row(128B)
    int scol = (tid & 7) * 8;
    float4v acc[4][2] = {{{0.f,0.f,0.f,0.f},{0.f,0.f,0.f,0.f}},
                         {{0.f,0.f,0.f,0.f},{0.f,0.f,0.f,0.f}},
                         {{0.f,0.f,0.f,0.f},{0.f,0.f,0.f,0.f}},
                         {{0.f,0.f,0.f,0.f},{0.f,0.f,0.f,0.f}}};
    int a_off = (wm0 + (lane & 15)) * 64 + (lane >> 4) * 8;
    int b_off = (wn0 + (lane & 15)) * 64 + (lane >> 4) * 8;
    for (int ks = 0; ks < ksteps; ks++) {
        int k0 = ks * 64;
        #pragma unroll
        for (int r = 0; r < 4; r++) {
            const ushort_t* g = A + (size_t)(m0 + r * 32 + srow) * lda + k0 + scol;
            async_cp16(g, As + (r * 256 + tid) * 8);
        }
        #pragma unroll
        for (int r = 0; r < 2; r++) {
            const ushort_t* g = Bt + (size_t)(n0 + r * 32 + srow) * lda + k0 + scol;
            async_cp16(g, Bs + (r * 256 + tid) * 8);
        }
        __syncthreads();
        #pragma unroll
        for (int kh = 0; kh < 2; kh++) {
            short8v b0 = *(const short8v*)&Bs[b_off + kh * 32];
            short8v b1 = *(const short8v*)&Bs[b_off + 16 * 64 + kh * 32];
            #pragma unroll
            for (int mi = 0; mi < 4; mi++) {
                short8v a = *(const short8v*)&As[a_off + mi * 16 * 64 + kh * 32];
                acc[mi][0] = __builtin_amdgcn_mfma_f32_16x16x32_bf16(a, b0, acc[mi][0], 0, 0, 0);
                acc[mi][1] = __builtin_amdgcn_mfma_f32_16x16x32_bf16(a, b1, acc[mi][1], 0, 0, 0);
            }
        }
        __syncthreads();
    }
    int lm = m0 + wm0 + (lane >> 4) * 4;
    int lc = n0 + wn0 + (lane & 15);
    #pragma unroll
    for (int mi = 0; mi < 4; mi++) {
        #pragma unroll
        for (int ni = 0; ni < 2; ni++) {
            int col = lc + ni * 16;
            if (col >= Nv) continue;
            #pragma unroll
            for (int r = 0; r < 4; r++) {
                int row = lm + mi * 16 + r;
                if (row >= M) continue;
                if (bf16out) ((ushort_t*)C)[(size_t)row * ldc + col] = f2bf(acc[mi][ni][r]);
                else         ((float*)C)[(size_t)row * ldc + col] = acc[mi][ni][r];
            }
        }
    }
}

// ---------------- GAT attention logits (bf16 h) ----------------
__global__ __launch_bounds__(256) void k_att(const ushort_t* __restrict__ hb, const float* __restrict__ att_s,
                                             const float* __restrict__ att_d, float* __restrict__ a_s,
                                             float* __restrict__ a_d) {
    int tid = blockIdx.x * 256 + threadIdx.x;
    if (tid >= NN * NHEAD) return;
    int n = tid / NHEAD, hd = tid % NHEAD;
    const ushort_t* hr = hb + (size_t)n * KPAD + hd * FH;
    const float* ws = att_s + hd * FH;
    const float* wd = att_d + hd * FH;
    float as = 0.f, ad = 0.f;
    #pragma unroll
    for (int c = 0; c < FH; c++) {
        float v = __uint_as_float(((unsigned)hr[c]) << 16);
        as += v * ws[c]; ad += v * wd[c];
    }
    a_s[tid] = as;
    a_d[tid] = ad;
}

// ---------------- GAT aggregate: wave per node, single pass, no max (softmax shift-invariant) ----------------
__global__ __launch_bounds__(256) void k_gat_agg(const ushort_t* __restrict__ hb, const float* __restrict__ a_s,
                                                 const float* __restrict__ a_d,
                                                 const int* __restrict__ csr_src,
                                                 const int* __restrict__ offs, const int* __restrict__ deg,
                                                 const float* __restrict__ b_gat,
                                                 ushort_t* __restrict__ xg1b, float* __restrict__ denArr) {
    int wid = (blockIdx.x * blockDim.x + threadIdx.x) >> 6;
    int lane = threadIdx.x & 63;
    if (wid >= NN) return;
    int o0 = offs[wid], d = deg[wid];
    bool mine = (lane < NHEAD);
    float adv = mine ? a_d[wid * NHEAD + lane] : 0.f;
    int hA0 = (2 * lane) / 35,       hA1 = (2 * lane + 1) / 35;
    int hB0 = (128 + 2 * lane) / 35, hB1 = (129 + 2 * lane) / 35;
    int hC0 = (256 + 2 * lane) / 35, hC1 = (257 + 2 * lane) / 35;   // ==10 for pad cols (h=0 there)
    float den = 0.f;
    float aL0 = 0.f, aH0 = 0.f, aL1 = 0.f, aH1 = 0.f, aL2 = 0.f, aH2 = 0.f;
    const unsigned* hb32 = (const unsigned*)hb;
    for (int i = 0; i < d; i++) {
        int s = csr_src[o0 + i];
        float asv = mine ? a_s[s * NHEAD + lane] : 0.f;
        float ex = __expf(lrelu(asv + adv));    // lanes>=10: exp(0)=1, only multiplies h-pad zeros
        den += ex;
        const unsigned* hr = hb32 + (size_t)s * (KPAD / 2);
        unsigned u0 = hr[lane], u1 = hr[lane + 64], u2 = hr[lane + 128];
        aL0 += __shfl(ex, hA0) * bflo(u0);  aH0 += __shfl(ex, hA1) * bfhi(u0);
        aL1 += __shfl(ex, hB0) * bflo(u1);  aH1 += __shfl(ex, hB1) * bfhi(u1);
        aL2 += __shfl(ex, hC0) * bflo(u2);  aH2 += __shfl(ex, hC1) * bfhi(u2);
    }
    float rden = 1.f / (den + 1e-16f);
    if (mine) denArr[wid * NHEAD + lane] = den;
    unsigned* orow = (unsigned*)(xg1b + (size_t)wid * KPAD);
    {
        int f = 2 * lane;
        float v0 = fmaxf(aL0 * __shfl(rden, hA0) + b_gat[f], 0.f);
        float v1 = fmaxf(aH0 * __shfl(rden, hA1) + b_gat[f + 1], 0.f);
        orow[lane] = packbf(v0, v1);
    }
    {
        int f = 128 + 2 * lane;
        float v0 = fmaxf(aL1 * __shfl(rden, hB0) + b_gat[f], 0.f);
        float v1 = fmaxf(aH1 * __shfl(rden, hB1) + b_gat[f + 1], 0.f);
        orow[lane + 64] = packbf(v0, v1);
    }
    {
        int f = 256 + 2 * lane;
        unsigned pv = 0;
        if (f < FG) {
            float v0 = fmaxf(aL2 * __shfl(rden, hC0) + b_gat[f], 0.f);
            float v1 = fmaxf(aH2 * __shfl(rden, hC1) + b_gat[f + 1], 0.f);
            pv = packbf(v0, v1);
        }
        orow[lane + 128] = pv;
    }
}

// ---------------- alpha in original edge order (coalesced writes; a_s/a_d/den are L2-resident) ----------------
__global__ __launch_bounds__(256) void k_alpha(const int* __restrict__ ei, const float* __restrict__ a_s,
                                               const float* __restrict__ a_d, const float* __restrict__ den,
                                               float* __restrict__ alphaOut) {
    int i = blockIdx.x * 256 + threadIdx.x;
    if (i >= ETOT * NHEAD) return;
    int e = i / NHEAD, hd = i % NHEAD;
    int s, dst;
    if (e < EE) { s = ei[e]; dst = ei[EE + e]; }
    else { s = dst = e - EE; }
    float ex = __expf(lrelu(a_s[s * NHEAD + hd] + a_d[dst * NHEAD + hd]));
    alphaOut[i] = ex / (den[dst * NHEAD + hd] + 1e-16f);
}

// ---------------- GCN aggregate: wave per node (bf16 h2 gathers) ----------------
__global__ __launch_bounds__(256) void k_gcn_agg(const ushort_t* __restrict__ h2b,
                                                 const int* __restrict__ csr_src,
                                                 const int* __restrict__ offs, const int* __restrict__ deg,
                                                 const float* __restrict__ dinv, const float* __restrict__ b_gcn,
                                                 float* __restrict__ xg2) {
    int wid = (blockIdx.x * blockDim.x + threadIdx.x) >> 6;
    int lane = threadIdx.x & 63;
    if (wid >= NN) return;
    int o0 = offs[wid], d = deg[wid];
    float wv = dinv[wid];
    float aL0 = 0.f, aH0 = 0.f, aL1 = 0.f, aH1 = 0.f, aL2 = 0.f, aH2 = 0.f;
    const unsigned* h32 = (const unsigned*)h2b;
    for (int i = 0; i < d; i++) {
        int s = csr_src[o0 + i];
        float ws = dinv[s];
        const unsigned* hr = h32 + (size_t)s * (KPAD / 2);
        unsigned u0 = hr[lane], u1 = hr[lane + 64], u2 = hr[lane + 128];
        aL0 += ws * bflo(u0);  aH0 += ws * bfhi(u0);
        aL1 += ws * bflo(u1);  aH1 += ws * bfhi(u1);
        aL2 += ws * bflo(u2);  aH2 += ws * bfhi(u2);
    }
    float* orow = xg2 + (size_t)wid * FG;
    {
        int f = 2 * lane;
        float2 v = { fmaxf(wv * aL0 + b_gcn[f], 0.f), fmaxf(wv * aH0 + b_gcn[f + 1], 0.f) };
        *(float2*)&orow[f] = v;
    }
    {
        int f = 128 + 2 * lane;
        float2 v = { fmaxf(wv * aL1 + b_gcn[f], 0.f), fmaxf(wv * aH1 + b_gcn[f + 1], 0.f) };
        *(float2*)&orow[f] = v;
    }
    {
        int f = 256 + 2 * lane;
        if (f < FG) {
            float2 v = { fmaxf(wv * aL2 + b_gcn[f], 0.f), fmaxf(wv * aH2 + b_gcn[f + 1], 0.f) };
            *(float2*)&orow[f] = v;
        }
    }
}

// ---------------- per-graph max+mean pool ----------------
__device__ __forceinline__ int lowerB(const int* a, int n, int key) {
    int lo = 0, hi = n;
    while (lo < hi) { int mid = (lo + hi) >> 1; if (a[mid] < key) lo = mid + 1; else hi = mid; }
    return lo;
}

__global__ __launch_bounds__(384) void k_pool(const float* __restrict__ xg2, const int* __restrict__ batch,
                                              float* __restrict__ pooled) {
    int g = blockIdx.x;
    int f = threadIdx.x;
    int s = lowerB(batch, NN, g);
    int e = lowerB(batch, NN, g + 1);
    if (f >= FG) return;
    float mx = -INFINITY, sm = 0.f;
    for (int n = s; n < e; n++) {
        float v = xg2[(size_t)n * FG + f];
        mx = fmaxf(mx, v);
        sm += v;
    }
    int cnt = e - s;
    pooled[g * 700 + f] = mx;
    pooled[g * 700 + FG + f] = sm / fmaxf((float)cnt, 1.f);
}

// ---------------- protein conv branch ----------------
__global__ __launch_bounds__(256) void k_conv(const int* __restrict__ target, const float* __restrict__ emb,
                                              const float* __restrict__ Wc, const float* __restrict__ bc,
                                              float* __restrict__ xt) {
    int tid = blockIdx.x * 256 + threadIdx.x;
    if (tid >= BB * 560) return;
    int b = tid / 560;
    int r = tid % 560;
    int f = r / 35, t = r % 35;
    float acc = bc[f];
    const int* tg = target + b * LL;
    const float* wf = Wc + f * 1024;
    for (int k = 0; k < 8; k++) {
        const float* er = emb + tg[t + k] * 128;
        const float* wk = wf + k;
        #pragma unroll 16
        for (int e = 0; e < 128; e++) acc += er[e] * wk[e * 8];
    }
    xt[tid] = acc;
}

// ---------------- final dot + sigmoid ----------------
__global__ __launch_bounds__(256) void k_out(const float* __restrict__ f1, const float* __restrict__ W_out,
                                             const float* __restrict__ b_out, float* __restrict__ out) {
    int wid = (blockIdx.x * blockDim.x + threadIdx.x) >> 6;
    int lane = threadIdx.x & 63;
    if (wid >= BB) return;
    const float* xr = f1 + (size_t)wid * 512;
    float acc = 0.f;
    #pragma unroll
    for (int k = 0; k < 8; k++) acc += xr[lane + k * 64] * W_out[lane + k * 64];
    #pragma unroll
    for (int d = 32; d; d >>= 1) acc += __shfl_xor(acc, d);
    if (lane == 0) out[wid] = 1.f / (1.f + __expf(-(acc + b_out[0])));
}

// ---------------- host launcher ----------------
extern "C" void kernel_launch(void* const* d_in, const int* in_sizes, int n_in,
                              void* d_out, int out_size, void* d_ws, size_t ws_size,
                              hipStream_t stream) {
    const float* x      = (const float*)d_in[0];
    const int*   ei     = (const int*)d_in[1];
    const int*   batch  = (const int*)d_in[2];
    const int*   target = (const int*)d_in[3];
    const float* W_gat  = (const float*)d_in[4];
    const float* att_s  = (const float*)d_in[5];
    const float* att_d  = (const float*)d_in[6];
    const float* b_gat  = (const float*)d_in[7];
    const float* W_gcn  = (const float*)d_in[8];
    const float* b_gcn  = (const float*)d_in[9];
    const float* W_fcg1 = (const float*)d_in[10];
    const float* b_fcg1 = (const float*)d_in[11];
    const float* W_fcg2 = (const float*)d_in[12];
    const float* b_fcg2 = (const float*)d_in[13];
    const float* embxt  = (const float*)d_in[14];
    const float* W_conv = (const float*)d_in[15];
    const float* b_conv = (const float*)d_in[16];
    const float* W_fcxt = (const float*)d_in[17];
    const float* b_fcxt = (const float*)d_in[18];
    const float* W_fc1  = (const float*)d_in[19];
    const float* b_fc1  = (const float*)d_in[20];
    const float* W_out  = (const float*)d_in[21];
    const float* b_out  = (const float*)d_in[22];

    float* out_sig  = (float*)d_out;          // [500]
    float* alphaOut = (float*)d_out + BB;     // [850000 * 10]

    size_t o = 0;
    auto alloc = [&](size_t bytes) -> void* {
        o = (o + 255) & ~(size_t)255;
        void* p = (char*)d_ws + o;
        o += bytes;
        return p;
    };
    int*   deg     = (int*)alloc((size_t)NN * 4);
    int*   cur     = (int*)alloc((size_t)NN * 4);
    int*   offs    = (int*)alloc((size_t)NN * 4);
    int*   part    = (int*)alloc(128 * 4);
    int*   pscan   = (int*)alloc(128 * 4);
    int*   csr_src = (int*)alloc((size_t)ETOT * 4);
    float* dinv    = (float*)alloc((size_t)NN * 4);
    float* a_s     = (float*)alloc((size_t)NN * NHEAD * 4);
    float* a_d     = (float*)alloc((size_t)NN * NHEAD * 4);
    float* denArr  = (float*)alloc((size_t)NN * NHEAD * 4);
    ushort_t* xb16 = (ushort_t*)alloc((size_t)MPAD * 64 * 2);
    ushort_t* WtGA = (ushort_t*)alloc((size_t)KPAD * 64 * 2);
    ushort_t* WtGC = (ushort_t*)alloc((size_t)KPAD * KPAD * 2);
    float* pooled  = (float*)alloc((size_t)BB * 700 * 4);
    ushort_t* hb   = (ushort_t*)alloc((size_t)MPAD * KPAD * 2);   // h (GAT), later h2 (GCN out)
    char*  R2      = (char*)alloc((size_t)NN * FG * 4);           // 70 MB aliased region
    ushort_t* xg1b = (ushort_t*)R2;                               // [MPAD][KPAD] bf16 (38.4 MB)
    float* xg2     = (float*)R2;                                  // [NN][FG] f32, after xg1b dead
    float* t1      = (float*)alloc((size_t)BB * 1500 * 4);
    float* xt      = (float*)alloc((size_t)BB * 560 * 4);
    float* xc      = (float*)alloc((size_t)BB * 256 * 4);
    float* f1      = (float*)alloc((size_t)BB * 512 * 4);
    (void)ws_size; (void)n_in; (void)in_sizes; (void)out_size;

    auto fc = [&](const float* A, const float* Bm, const float* bias, float* C,
                  int M, int N, int K, int ldc, int act) {
        int ntiles = (N + 63) / 64;
        int waves = M * ntiles;
        k_fc<<<(waves + 3) / 4, 256, 0, stream>>>(A, Bm, bias, C, M, N, K, ldc, act);
    };

    // graph prep
    k_init<<<(NN + 255) / 256, 256, 0, stream>>>(deg, cur);
    k_deg<<<(EE + 255) / 256, 256, 0, stream>>>(ei, deg);
    k_scan1<<<NCHUNK, 512, 0, stream>>>(deg, part);
    k_scan2<<<1, 64, 0, stream>>>(part, pscan);
    k_scan3<<<NCHUNK, 512, 0, stream>>>(deg, pscan, offs);
    k_scatter<<<(ETOT + 255) / 256, 256, 0, stream>>>(ei, offs, cur, csr_src);
    k_dinv<<<(NN + 255) / 256, 256, 0, stream>>>(deg, dinv);

    // bf16 prep
    k_prep_x<<<(MPAD * 64 + 255) / 256, 256, 0, stream>>>(x, xb16);
    k_prep_wgat<<<(KPAD * 64 + 255) / 256, 256, 0, stream>>>(W_gat, WtGA);
    k_prep_wgcn<<<(KPAD * KPAD + 255) / 256, 256, 0, stream>>>(W_gcn, WtGC);
    k_zero_tail<<<((MPAD - NN) * KPAD + 255) / 256, 256, 0, stream>>>(xg1b);

    // GAT: h = x @ W_gat  (bf16 MFMA, bf16 out)
    {
        dim3 g(KPAD / 64, MPAD / 128);
        k_mfma<<<g, 256, 0, stream>>>(xb16, WtGA, hb, MPAD, KPAD, KPAD, 64, 1, 1);
    }
    k_att<<<(NN * NHEAD + 255) / 256, 256, 0, stream>>>(hb, att_s, att_d, a_s, a_d);
    k_gat_agg<<<(NN + 3) / 4, 256, 0, stream>>>(hb, a_s, a_d, csr_src, offs, deg, b_gat, xg1b, denArr);
    k_alpha<<<(ETOT * NHEAD + 255) / 256, 256, 0, stream>>>(ei, a_s, a_d, denArr, alphaOut);

    // GCN: h2 = xg1 @ W_gcn (bf16 MFMA, bf16 out, overwrites hb region)
    {
        dim3 g(KPAD / 64, MPAD / 128);
        k_mfma<<<g, 256, 0, stream>>>(xg1b, WtGC, hb, MPAD, KPAD, KPAD, KPAD, KPAD / 64, 1);
    }
    k_gcn_agg<<<(NN + 3) / 4, 256, 0, stream>>>(hb, csr_src, offs, deg, dinv, b_gcn, xg2);

    // pool + FC stacks
    k_pool<<<BB, 384, 0, stream>>>(xg2, batch, pooled);
    fc(pooled, W_fcg1, b_fcg1, t1, BB, 1500, 700, 1500, 1);
    fc(t1, W_fcg2, b_fcg2, xc, BB, 128, 1500, 256, 0);
    k_conv<<<(BB * 560 + 255) / 256, 256, 0, stream>>>(target, embxt, W_conv, b_conv, xt);
    fc(xt, W_fcxt, b_fcxt, xc + 128, BB, 128, 560, 256, 0);
    fc(xc, W_fc1, b_fc1, f1, BB, 512, 256, 512, 1);
    k_out<<<(BB + 3) / 4, 256, 0, stream>>>(f1, W_out, b_out, out_sig);
}

// Round 5
// 795.158 us; speedup vs baseline: 2.5324x; 1.2542x over previous
//
#include <hip/hip_runtime.h>
#include <math.h>

#define NN 50000
#define EE 800000
#define BB 500
#define LL 42
#define NHEAD 10
#define FH 35
#define FG 350
#define ETOT (EE + NN)
#define NCHUNK ((NN + 511) / 512)

#define KPAD 384         // bf16 row stride for h / xg1 / h2
#define MPAD 50048       // M padded to multiple of 128

typedef unsigned short ushort_t;
typedef __attribute__((ext_vector_type(8))) short short8v;
typedef __attribute__((ext_vector_type(4))) float float4v;

__device__ __forceinline__ float lrelu(float x) { return x > 0.f ? x : 0.2f * x; }

__device__ __forceinline__ ushort_t f2bf(float f) {
    unsigned int u = __float_as_uint(f);
    u += 0x7fffu + ((u >> 16) & 1u);      // round-to-nearest-even
    return (ushort_t)(u >> 16);
}
__device__ __forceinline__ float bflo(unsigned u) { return __uint_as_float(u << 16); }
__device__ __forceinline__ float bfhi(unsigned u) { return __uint_as_float(u & 0xffff0000u); }
__device__ __forceinline__ unsigned packbf(float a, float b) {
    return (unsigned)f2bf(a) | ((unsigned)f2bf(b) << 16);
}

__device__ __forceinline__ void async_cp16(const void* g, void* l) {
    __builtin_amdgcn_global_load_lds((const __attribute__((address_space(1))) unsigned int*)g,
                                     (__attribute__((address_space(3))) unsigned int*)l, 16, 0, 0);
}

// ---------------- graph prep ----------------
__global__ __launch_bounds__(256) void k_init(int* deg, int* cur) {
    int i = blockIdx.x * 256 + threadIdx.x;
    if (i < NN) { deg[i] = 1; cur[i] = 0; }   // deg=1 accounts for the self-loop
}

__global__ __launch_bounds__(256) void k_deg(const int* __restrict__ ei, int* deg) {
    int i = blockIdx.x * 256 + threadIdx.x;
    if (i < EE) atomicAdd(&deg[ei[EE + i]], 1);
}

__global__ __launch_bounds__(512) void k_scan1(const int* __restrict__ deg, int* part) {
    int i = blockIdx.x * 512 + threadIdx.x;
    int lane = threadIdx.x & 63, wv = threadIdx.x >> 6;
    int x = (i < NN) ? deg[i] : 0;
    #pragma unroll
    for (int d = 32; d; d >>= 1) x += __shfl_xor(x, d);
    __shared__ int wsum[8];
    if (lane == 0) wsum[wv] = x;
    __syncthreads();
    if (threadIdx.x == 0) {
        int s = 0;
        #pragma unroll
        for (int w = 0; w < 8; w++) s += wsum[w];
        part[blockIdx.x] = s;
    }
}

__global__ __launch_bounds__(64) void k_scan2(const int* __restrict__ part, int* pscan) {
    int l = threadIdx.x;
    int v0 = (l < NCHUNK) ? part[l] : 0;
    #pragma unroll
    for (int d = 1; d < 64; d <<= 1) { int t = __shfl_up(v0, d); if (l >= d) v0 += t; }
    int tot0 = __shfl(v0, 63);
    int v1 = (64 + l < NCHUNK) ? part[64 + l] : 0;
    #pragma unroll
    for (int d = 1; d < 64; d <<= 1) { int t = __shfl_up(v1, d); if (l >= d) v1 += t; }
    v1 += tot0;
    if (l < NCHUNK) pscan[l] = v0;
    if (64 + l < NCHUNK) pscan[64 + l] = v1;
}

__global__ __launch_bounds__(512) void k_scan3(const int* __restrict__ deg, const int* __restrict__ pscan,
                                               int* offs) {
    int i = blockIdx.x * 512 + threadIdx.x;
    int lane = threadIdx.x & 63, wv = threadIdx.x >> 6;
    int x = (i < NN) ? deg[i] : 0;
    int incl = x;
    #pragma unroll
    for (int d = 1; d < 64; d <<= 1) { int t = __shfl_up(incl, d); if (lane >= d) incl += t; }
    __shared__ int wtot[8];
    if (lane == 63) wtot[wv] = incl;
    __syncthreads();
    int woff = 0;
    for (int w = 0; w < wv; w++) woff += wtot[w];
    int base = (blockIdx.x == 0) ? 0 : pscan[blockIdx.x - 1];
    if (i < NN) offs[i] = base + woff + incl - x;   // exclusive prefix
}

__global__ __launch_bounds__(256) void k_scatter(const int* __restrict__ ei, const int* __restrict__ offs,
                                                 int* cur, int* csr_src) {
    int i = blockIdx.x * 256 + threadIdx.x;
    if (i < EE) {
        int s = ei[i], d = ei[EE + i];
        int slot = atomicAdd(&cur[d], 1);
        csr_src[offs[d] + slot] = s;
    } else if (i < ETOT) {
        int v = i - EE;
        int slot = atomicAdd(&cur[v], 1);
        csr_src[offs[v] + slot] = v;
    }
}

__global__ __launch_bounds__(256) void k_dinv(const int* __restrict__ deg, float* dinv) {
    int i = blockIdx.x * 256 + threadIdx.x;
    if (i < NN) dinv[i] = rsqrtf((float)deg[i]);
}

// ---------------- weight / input prep (f32 -> padded transposed bf16) ----------------
__global__ __launch_bounds__(256) void k_prep_x(const float* __restrict__ x, ushort_t* __restrict__ xb) {
    int i = blockIdx.x * 256 + threadIdx.x;
    if (i >= MPAD * 64) return;
    int r = i / 64, k = i % 64;
    float v = (r < NN && k < 35) ? x[r * 35 + k] : 0.f;
    xb[i] = f2bf(v);
}

__global__ __launch_bounds__(256) void k_prep_wgat(const float* __restrict__ W, ushort_t* __restrict__ Wt) {
    int i = blockIdx.x * 256 + threadIdx.x;
    if (i >= KPAD * 64) return;
    int n = i / 64, k = i % 64;
    float v = (n < FG && k < 35) ? W[k * FG + n] : 0.f;
    Wt[i] = f2bf(v);
}

__global__ __launch_bounds__(256) void k_prep_wgcn(const float* __restrict__ W, ushort_t* __restrict__ Wt) {
    int i = blockIdx.x * 256 + threadIdx.x;
    if (i >= KPAD * KPAD) return;
    int n = i / KPAD, k = i % KPAD;
    float v = (n < FG && k < FG) ? W[k * FG + n] : 0.f;
    Wt[i] = f2bf(v);
}

// zero pad rows 50000..50047 of xg1b so GEMM A-staging reads defined data
__global__ __launch_bounds__(256) void k_zero_tail(ushort_t* xg1b) {
    int i = blockIdx.x * 256 + threadIdx.x;
    int total = (MPAD - NN) * KPAD;
    if (i < total) xg1b[(size_t)NN * KPAD + i] = 0;
}

// ---------------- latency-oriented FC: row-per-wave, 64-col tiles, K unroll x8 ----------------
// C[m*ldc+col] = act(sum_k A[m*K+k]*B[k*N+col] + bias[col])
__global__ __launch_bounds__(256) void k_fc(const float* __restrict__ A, const float* __restrict__ B,
                                            const float* __restrict__ bias, float* __restrict__ C,
                                            int M, int N, int K, int ldc, int act) {
    int gw = (blockIdx.x * 256 + threadIdx.x) >> 6;
    int lane = threadIdx.x & 63;
    int ntiles = (N + 63) >> 6;
    int m = gw / ntiles, ct = gw % ntiles;
    if (m >= M) return;
    int col = ct * 64 + lane;
    bool ok = col < N;
    int colc = ok ? col : (N - 1);            // clamp for safe loads
    const float* Ar = A + (size_t)m * K;
    const float* Bc = B + colc;
    float acc = 0.f;
    int k = 0;
    for (; k + 8 <= K; k += 8) {
        float4 a0 = *(const float4*)&Ar[k];
        float4 a1 = *(const float4*)&Ar[k + 4];
        float b0 = Bc[(size_t)(k + 0) * N];
        float b1 = Bc[(size_t)(k + 1) * N];
        float b2 = Bc[(size_t)(k + 2) * N];
        float b3 = Bc[(size_t)(k + 3) * N];
        float b4 = Bc[(size_t)(k + 4) * N];
        float b5 = Bc[(size_t)(k + 5) * N];
        float b6 = Bc[(size_t)(k + 6) * N];
        float b7 = Bc[(size_t)(k + 7) * N];
        acc += a0.x * b0 + a0.y * b1 + a0.z * b2 + a0.w * b3;
        acc += a1.x * b4 + a1.y * b5 + a1.z * b6 + a1.w * b7;
    }
    for (; k < K; k++) acc += Ar[k] * Bc[(size_t)k * N];
    if (ok) {
        float v = acc + bias[col];
        if (act) v = fmaxf(v, 0.f);
        C[(size_t)m * ldc + col] = v;
    }
}

// ---------------- bf16 MFMA GEMM: C = A[Mpad,lda](bf16) @ Bt[Npad,lda](bf16,n-major) ----------------
// tile 128x64, BK=64, 4 waves in 2x2, wave tile 64x32 (4x2 fragments of 16x16x32)
__global__ __launch_bounds__(256) void k_mfma(const ushort_t* __restrict__ A, const ushort_t* __restrict__ Bt,
                                              void* __restrict__ C, int M, int Nv, int ldc, int lda,
                                              int ksteps, int bf16out) {
    __shared__ ushort_t As[128 * 64];
    __shared__ ushort_t Bs[64 * 64];
    int tid = threadIdx.x;
    int wid = tid >> 6, lane = tid & 63;
    int m0 = blockIdx.y * 128, n0 = blockIdx.x * 64;
    int wm0 = (wid >> 1) * 64, wn0 = (wid & 1) * 32;
    int srow = tid >> 3;              // staging: 8 lanes x 16B per row(128B)
    int scol = (tid & 7) * 8;
    float4v acc[4][2] = {{{0.f,0.f,0.f,0.f},{0.f,0.f,0.f,0.f}},
                         {{0.f,0.f,0.f,0.f},{0.f,0.f,0.f,0.f}},
                         {{0.f,0.f,0.f,0.f},{0.f,0.f,0.f,0.f}},
                         {{0.f,0.f,0.f,0.f},{0.f,0.f,0.f,0.f}}};
    int a_off = (wm0 + (lane & 15)) * 64 + (lane >> 4) * 8;
    int b_off = (wn0 + (lane & 15)) * 64 + (lane >> 4) * 8;
    for (int ks = 0; ks < ksteps; ks++) {
        int k0 = ks * 64;
        #pragma unroll
        for (int r = 0; r < 4; r++) {
            const ushort_t* g = A + (size_t)(m0 + r * 32 + srow) * lda + k0 + scol;
            async_cp16(g, As + (r * 256 + tid) * 8);
        }
        #pragma unroll
        for (int r = 0; r < 2; r++) {
            const ushort_t* g = Bt + (size_t)(n0 + r * 32 + srow) * lda + k0 + scol;
            async_cp16(g, Bs + (r * 256 + tid) * 8);
        }
        __syncthreads();
        #pragma unroll
        for (int kh = 0; kh < 2; kh++) {
            short8v b0 = *(const short8v*)&Bs[b_off + kh * 32];
            short8v b1 = *(const short8v*)&Bs[b_off + 16 * 64 + kh * 32];
            #pragma unroll
            for (int mi = 0; mi < 4; mi++) {
                short8v a = *(const short8v*)&As[a_off + mi * 16 * 64 + kh * 32];
                acc[mi][0] = __builtin_amdgcn_mfma_f32_16x16x32_bf16(a, b0, acc[mi][0], 0, 0, 0);
                acc[mi][1] = __builtin_amdgcn_mfma_f32_16x16x32_bf16(a, b1, acc[mi][1], 0, 0, 0);
            }
        }
        __syncthreads();
    }
    int lm = m0 + wm0 + (lane >> 4) * 4;
    int lc = n0 + wn0 + (lane & 15);
    #pragma unroll
    for (int mi = 0; mi < 4; mi++) {
        #pragma unroll
        for (int ni = 0; ni < 2; ni++) {
            int col = lc + ni * 16;
            if (col >= Nv) continue;
            #pragma unroll
            for (int r = 0; r < 4; r++) {
                int row = lm + mi * 16 + r;
                if (row >= M) continue;
                if (bf16out) ((ushort_t*)C)[(size_t)row * ldc + col] = f2bf(acc[mi][ni][r]);
                else         ((float*)C)[(size_t)row * ldc + col] = acc[mi][ni][r];
            }
        }
    }
}

// ---------------- GAT attention logits (bf16 h) ----------------
__global__ __launch_bounds__(256) void k_att(const ushort_t* __restrict__ hb, const float* __restrict__ att_s,
                                             const float* __restrict__ att_d, float* __restrict__ a_s,
                                             float* __restrict__ a_d) {
    int tid = blockIdx.x * 256 + threadIdx.x;
    if (tid >= NN * NHEAD) return;
    int n = tid / NHEAD, hd = tid % NHEAD;
    const ushort_t* hr = hb + (size_t)n * KPAD + hd * FH;
    const float* ws = att_s + hd * FH;
    const float* wd = att_d + hd * FH;
    float as = 0.f, ad = 0.f;
    #pragma unroll
    for (int c = 0; c < FH; c++) {
        float v = __uint_as_float(((unsigned)hr[c]) << 16);
        as += v * ws[c]; ad += v * wd[c];
    }
    a_s[tid] = as;
    a_d[tid] = ad;
}

// ---------------- GAT aggregate: wave per node, single pass, no max (softmax shift-invariant) ----------------
__global__ __launch_bounds__(256) void k_gat_agg(const ushort_t* __restrict__ hb, const float* __restrict__ a_s,
                                                 const float* __restrict__ a_d,
                                                 const int* __restrict__ csr_src,
                                                 const int* __restrict__ offs, const int* __restrict__ deg,
                                                 const float* __restrict__ b_gat,
                                                 ushort_t* __restrict__ xg1b, float* __restrict__ denArr) {
    int wid = (blockIdx.x * blockDim.x + threadIdx.x) >> 6;
    int lane = threadIdx.x & 63;
    if (wid >= NN) return;
    int o0 = offs[wid], d = deg[wid];
    bool mine = (lane < NHEAD);
    float adv = mine ? a_d[wid * NHEAD + lane] : 0.f;
    int hA0 = (2 * lane) / 35,       hA1 = (2 * lane + 1) / 35;
    int hB0 = (128 + 2 * lane) / 35, hB1 = (129 + 2 * lane) / 35;
    int hC0 = (256 + 2 * lane) / 35, hC1 = (257 + 2 * lane) / 35;   // ==10 for pad cols (h=0 there)
    float den = 0.f;
    float aL0 = 0.f, aH0 = 0.f, aL1 = 0.f, aH1 = 0.f, aL2 = 0.f, aH2 = 0.f;
    const unsigned* hb32 = (const unsigned*)hb;
    for (int i = 0; i < d; i++) {
        int s = csr_src[o0 + i];
        float asv = mine ? a_s[s * NHEAD + lane] : 0.f;
        float ex = __expf(lrelu(asv + adv));    // lanes>=10: exp(0)=1, only multiplies h-pad zeros
        den += ex;
        const unsigned* hr = hb32 + (size_t)s * (KPAD / 2);
        unsigned u0 = hr[lane], u1 = hr[lane + 64], u2 = hr[lane + 128];
        aL0 += __shfl(ex, hA0) * bflo(u0);  aH0 += __shfl(ex, hA1) * bfhi(u0);
        aL1 += __shfl(ex, hB0) * bflo(u1);  aH1 += __shfl(ex, hB1) * bfhi(u1);
        aL2 += __shfl(ex, hC0) * bflo(u2);  aH2 += __shfl(ex, hC1) * bfhi(u2);
    }
    float rden = 1.f / (den + 1e-16f);
    if (mine) denArr[wid * NHEAD + lane] = den;
    unsigned* orow = (unsigned*)(xg1b + (size_t)wid * KPAD);
    {
        int f = 2 * lane;
        float v0 = fmaxf(aL0 * __shfl(rden, hA0) + b_gat[f], 0.f);
        float v1 = fmaxf(aH0 * __shfl(rden, hA1) + b_gat[f + 1], 0.f);
        orow[lane] = packbf(v0, v1);
    }
    {
        int f = 128 + 2 * lane;
        float v0 = fmaxf(aL1 * __shfl(rden, hB0) + b_gat[f], 0.f);
        float v1 = fmaxf(aH1 * __shfl(rden, hB1) + b_gat[f + 1], 0.f);
        orow[lane + 64] = packbf(v0, v1);
    }
    {
        int f = 256 + 2 * lane;
        unsigned pv = 0;
        if (f < FG) {
            float v0 = fmaxf(aL2 * __shfl(rden, hC0) + b_gat[f], 0.f);
            float v1 = fmaxf(aH2 * __shfl(rden, hC1) + b_gat[f + 1], 0.f);
            pv = packbf(v0, v1);
        }
        orow[lane + 128] = pv;
    }
}

// ---------------- alpha in original edge order (coalesced writes; a_s/a_d/den are L2-resident) ----------------
__global__ __launch_bounds__(256) void k_alpha(const int* __restrict__ ei, const float* __restrict__ a_s,
                                               const float* __restrict__ a_d, const float* __restrict__ den,
                                               float* __restrict__ alphaOut) {
    int i = blockIdx.x * 256 + threadIdx.x;
    if (i >= ETOT * NHEAD) return;
    int e = i / NHEAD, hd = i % NHEAD;
    int s, dst;
    if (e < EE) { s = ei[e]; dst = ei[EE + e]; }
    else { s = dst = e - EE; }
    float ex = __expf(lrelu(a_s[s * NHEAD + hd] + a_d[dst * NHEAD + hd]));
    alphaOut[i] = ex / (den[dst * NHEAD + hd] + 1e-16f);
}

// ---------------- GCN aggregate: wave per node (bf16 h2 gathers) ----------------
__global__ __launch_bounds__(256) void k_gcn_agg(const ushort_t* __restrict__ h2b,
                                                 const int* __restrict__ csr_src,
                                                 const int* __restrict__ offs, const int* __restrict__ deg,
                                                 const float* __restrict__ dinv, const float* __restrict__ b_gcn,
                                                 float* __restrict__ xg2) {
    int wid = (blockIdx.x * blockDim.x + threadIdx.x) >> 6;
    int lane = threadIdx.x & 63;
    if (wid >= NN) return;
    int o0 = offs[wid], d = deg[wid];
    float wv = dinv[wid];
    float aL0 = 0.f, aH0 = 0.f, aL1 = 0.f, aH1 = 0.f, aL2 = 0.f, aH2 = 0.f;
    const unsigned* h32 = (const unsigned*)h2b;
    for (int i = 0; i < d; i++) {
        int s = csr_src[o0 + i];
        float ws = dinv[s];
        const unsigned* hr = h32 + (size_t)s * (KPAD / 2);
        unsigned u0 = hr[lane], u1 = hr[lane + 64], u2 = hr[lane + 128];
        aL0 += ws * bflo(u0);  aH0 += ws * bfhi(u0);
        aL1 += ws * bflo(u1);  aH1 += ws * bfhi(u1);
        aL2 += ws * bflo(u2);  aH2 += ws * bfhi(u2);
    }
    float* orow = xg2 + (size_t)wid * FG;
    {
        int f = 2 * lane;
        float2 v = { fmaxf(wv * aL0 + b_gcn[f], 0.f), fmaxf(wv * aH0 + b_gcn[f + 1], 0.f) };
        *(float2*)&orow[f] = v;
    }
    {
        int f = 128 + 2 * lane;
        float2 v = { fmaxf(wv * aL1 + b_gcn[f], 0.f), fmaxf(wv * aH1 + b_gcn[f + 1], 0.f) };
        *(float2*)&orow[f] = v;
    }
    {
        int f = 256 + 2 * lane;
        if (f < FG) {
            float2 v = { fmaxf(wv * aL2 + b_gcn[f], 0.f), fmaxf(wv * aH2 + b_gcn[f + 1], 0.f) };
            *(float2*)&orow[f] = v;
        }
    }
}

// ---------------- per-graph max+mean pool ----------------
__device__ __forceinline__ int lowerB(const int* a, int n, int key) {
    int lo = 0, hi = n;
    while (lo < hi) { int mid = (lo + hi) >> 1; if (a[mid] < key) lo = mid + 1; else hi = mid; }
    return lo;
}

__global__ __launch_bounds__(384) void k_pool(const float* __restrict__ xg2, const int* __restrict__ batch,
                                              float* __restrict__ pooled) {
    int g = blockIdx.x;
    int f = threadIdx.x;
    int s = lowerB(batch, NN, g);
    int e = lowerB(batch, NN, g + 1);
    if (f >= FG) return;
    float mx = -INFINITY, sm = 0.f;
    for (int n = s; n < e; n++) {
        float v = xg2[(size_t)n * FG + f];
        mx = fmaxf(mx, v);
        sm += v;
    }
    int cnt = e - s;
    pooled[g * 700 + f] = mx;
    pooled[g * 700 + FG + f] = sm / fmaxf((float)cnt, 1.f);
}

// ---------------- protein conv branch: LDS-resident, 2 proteins per block ----------------
// thread item = (b_local, f_quad, t): acc[4] over k=0..7, e=0..127 via float4 LDS reads
__global__ __launch_bounds__(256) void k_conv(const int* __restrict__ target, const float* __restrict__ emb,
                                              const float* __restrict__ Wc, const float* __restrict__ bc,
                                              float* __restrict__ xt) {
    __shared__ float embL[26 * 132];        // rows padded to 132 floats (bank spread, 16B aligned)
    __shared__ float WL[16 * 8 * 128];      // WL[f][k][e] = Wc[f][e][k]
    __shared__ int   tgL[2 * LL];
    int tid = threadIdx.x;
    int b0 = blockIdx.x * 2;
    for (int i = tid; i < 26 * 128; i += 256) {
        int r = i >> 7, e = i & 127;
        embL[r * 132 + e] = emb[i];
    }
    for (int i = tid; i < 16384; i += 256) {
        int f = i >> 10, rem = i & 1023, k = rem >> 7, e = rem & 127;
        WL[i] = Wc[f * 1024 + e * 8 + k];
    }
    if (tid < 2 * LL) tgL[tid] = target[b0 * LL + tid];   // rows b0, b0+1 contiguous
    __syncthreads();
    #pragma unroll
    for (int pass = 0; pass < 2; pass++) {
        int r = tid + pass * 256;
        if (r >= 280) break;
        int bl = r / 140, rem = r % 140;
        int fq = rem / 35, t = rem % 35;
        const int* tg = &tgL[bl * LL];
        float ac0 = 0.f, ac1 = 0.f, ac2 = 0.f, ac3 = 0.f;
        for (int k = 0; k < 8; k++) {
            const float* er = &embL[tg[t + k] * 132];
            const float* w0 = &WL[((fq * 4 + 0) * 8 + k) * 128];
            const float* w1 = &WL[((fq * 4 + 1) * 8 + k) * 128];
            const float* w2 = &WL[((fq * 4 + 2) * 8 + k) * 128];
            const float* w3 = &WL[((fq * 4 + 3) * 8 + k) * 128];
            #pragma unroll 8
            for (int e = 0; e < 128; e += 4) {
                float4 a = *(const float4*)&er[e];
                float4 q0 = *(const float4*)&w0[e];
                float4 q1 = *(const float4*)&w1[e];
                float4 q2 = *(const float4*)&w2[e];
                float4 q3 = *(const float4*)&w3[e];
                ac0 += a.x * q0.x + a.y * q0.y + a.z * q0.z + a.w * q0.w;
                ac1 += a.x * q1.x + a.y * q1.y + a.z * q1.z + a.w * q1.w;
                ac2 += a.x * q2.x + a.y * q2.y + a.z * q2.z + a.w * q2.w;
                ac3 += a.x * q3.x + a.y * q3.y + a.z * q3.z + a.w * q3.w;
            }
        }
        int b = b0 + bl, fb = fq * 4;
        xt[b * 560 + (fb + 0) * 35 + t] = ac0 + bc[fb + 0];
        xt[b * 560 + (fb + 1) * 35 + t] = ac1 + bc[fb + 1];
        xt[b * 560 + (fb + 2) * 35 + t] = ac2 + bc[fb + 2];
        xt[b * 560 + (fb + 3) * 35 + t] = ac3 + bc[fb + 3];
    }
}

// ---------------- final dot + sigmoid ----------------
__global__ __launch_bounds__(256) void k_out(const float* __restrict__ f1, const float* __restrict__ W_out,
                                             const float* __restrict__ b_out, float* __restrict__ out) {
    int wid = (blockIdx.x * blockDim.x + threadIdx.x) >> 6;
    int lane = threadIdx.x & 63;
    if (wid >= BB) return;
    const float* xr = f1 + (size_t)wid * 512;
    float acc = 0.f;
    #pragma unroll
    for (int k = 0; k < 8; k++) acc += xr[lane + k * 64] * W_out[lane + k * 64];
    #pragma unroll
    for (int d = 32; d; d >>= 1) acc += __shfl_xor(acc, d);
    if (lane == 0) out[wid] = 1.f / (1.f + __expf(-(acc + b_out[0])));
}

// ---------------- host launcher ----------------
extern "C" void kernel_launch(void* const* d_in, const int* in_sizes, int n_in,
                              void* d_out, int out_size, void* d_ws, size_t ws_size,
                              hipStream_t stream) {
    const float* x      = (const float*)d_in[0];
    const int*   ei     = (const int*)d_in[1];
    const int*   batch  = (const int*)d_in[2];
    const int*   target = (const int*)d_in[3];
    const float* W_gat  = (const float*)d_in[4];
    const float* att_s  = (const float*)d_in[5];
    const float* att_d  = (const float*)d_in[6];
    const float* b_gat  = (const float*)d_in[7];
    const float* W_gcn  = (const float*)d_in[8];
    const float* b_gcn  = (const float*)d_in[9];
    const float* W_fcg1 = (const float*)d_in[10];
    const float* b_fcg1 = (const float*)d_in[11];
    const float* W_fcg2 = (const float*)d_in[12];
    const float* b_fcg2 = (const float*)d_in[13];
    const float* embxt  = (const float*)d_in[14];
    const float* W_conv = (const float*)d_in[15];
    const float* b_conv = (const float*)d_in[16];
    const float* W_fcxt = (const float*)d_in[17];
    const float* b_fcxt = (const float*)d_in[18];
    const float* W_fc1  = (const float*)d_in[19];
    const float* b_fc1  = (const float*)d_in[20];
    const float* W_out  = (const float*)d_in[21];
    const float* b_out  = (const float*)d_in[22];

    float* out_sig  = (float*)d_out;          // [500]
    float* alphaOut = (float*)d_out + BB;     // [850000 * 10]

    size_t o = 0;
    auto alloc = [&](size_t bytes) -> void* {
        o = (o + 255) & ~(size_t)255;
        void* p = (char*)d_ws + o;
        o += bytes;
        return p;
    };
    int*   deg     = (int*)alloc((size_t)NN * 4);
    int*   cur     = (int*)alloc((size_t)NN * 4);
    int*   offs    = (int*)alloc((size_t)NN * 4);
    int*   part    = (int*)alloc(128 * 4);
    int*   pscan   = (int*)alloc(128 * 4);
    int*   csr_src = (int*)alloc((size_t)ETOT * 4);
    float* dinv    = (float*)alloc((size_t)NN * 4);
    float* a_s     = (float*)alloc((size_t)NN * NHEAD * 4);
    float* a_d     = (float*)alloc((size_t)NN * NHEAD * 4);
    float* denArr  = (float*)alloc((size_t)NN * NHEAD * 4);
    ushort_t* xb16 = (ushort_t*)alloc((size_t)MPAD * 64 * 2);
    ushort_t* WtGA = (ushort_t*)alloc((size_t)KPAD * 64 * 2);
    ushort_t* WtGC = (ushort_t*)alloc((size_t)KPAD * KPAD * 2);
    float* pooled  = (float*)alloc((size_t)BB * 700 * 4);
    ushort_t* hb   = (ushort_t*)alloc((size_t)MPAD * KPAD * 2);   // h (GAT), later h2 (GCN out)
    char*  R2      = (char*)alloc((size_t)NN * FG * 4);           // 70 MB aliased region
    ushort_t* xg1b = (ushort_t*)R2;                               // [MPAD][KPAD] bf16 (38.4 MB)
    float* xg2     = (float*)R2;                                  // [NN][FG] f32, after xg1b dead
    float* t1      = (float*)alloc((size_t)BB * 1500 * 4);
    float* xt      = (float*)alloc((size_t)BB * 560 * 4);
    float* xc      = (float*)alloc((size_t)BB * 256 * 4);
    float* f1      = (float*)alloc((size_t)BB * 512 * 4);
    (void)ws_size; (void)n_in; (void)in_sizes; (void)out_size;

    auto fc = [&](const float* A, const float* Bm, const float* bias, float* C,
                  int M, int N, int K, int ldc, int act) {
        int ntiles = (N + 63) / 64;
        int waves = M * ntiles;
        k_fc<<<(waves + 3) / 4, 256, 0, stream>>>(A, Bm, bias, C, M, N, K, ldc, act);
    };

    // graph prep
    k_init<<<(NN + 255) / 256, 256, 0, stream>>>(deg, cur);
    k_deg<<<(EE + 255) / 256, 256, 0, stream>>>(ei, deg);
    k_scan1<<<NCHUNK, 512, 0, stream>>>(deg, part);
    k_scan2<<<1, 64, 0, stream>>>(part, pscan);
    k_scan3<<<NCHUNK, 512, 0, stream>>>(deg, pscan, offs);
    k_scatter<<<(ETOT + 255) / 256, 256, 0, stream>>>(ei, offs, cur, csr_src);
    k_dinv<<<(NN + 255) / 256, 256, 0, stream>>>(deg, dinv);

    // bf16 prep
    k_prep_x<<<(MPAD * 64 + 255) / 256, 256, 0, stream>>>(x, xb16);
    k_prep_wgat<<<(KPAD * 64 + 255) / 256, 256, 0, stream>>>(W_gat, WtGA);
    k_prep_wgcn<<<(KPAD * KPAD + 255) / 256, 256, 0, stream>>>(W_gcn, WtGC);
    k_zero_tail<<<((MPAD - NN) * KPAD + 255) / 256, 256, 0, stream>>>(xg1b);

    // GAT: h = x @ W_gat  (bf16 MFMA, bf16 out)
    {
        dim3 g(KPAD / 64, MPAD / 128);
        k_mfma<<<g, 256, 0, stream>>>(xb16, WtGA, hb, MPAD, KPAD, KPAD, 64, 1, 1);
    }
    k_att<<<(NN * NHEAD + 255) / 256, 256, 0, stream>>>(hb, att_s, att_d, a_s, a_d);
    k_gat_agg<<<(NN + 3) / 4, 256, 0, stream>>>(hb, a_s, a_d, csr_src, offs, deg, b_gat, xg1b, denArr);
    k_alpha<<<(ETOT * NHEAD + 255) / 256, 256, 0, stream>>>(ei, a_s, a_d, denArr, alphaOut);

    // GCN: h2 = xg1 @ W_gcn (bf16 MFMA, bf16 out, overwrites hb region)
    {
        dim3 g(KPAD / 64, MPAD / 128);
        k_mfma<<<g, 256, 0, stream>>>(xg1b, WtGC, hb, MPAD, KPAD, KPAD, KPAD, KPAD / 64, 1);
    }
    k_gcn_agg<<<(NN + 3) / 4, 256, 0, stream>>>(hb, csr_src, offs, deg, dinv, b_gcn, xg2);

    // pool + FC stacks
    k_pool<<<BB, 384, 0, stream>>>(xg2, batch, pooled);
    fc(pooled, W_fcg1, b_fcg1, t1, BB, 1500, 700, 1500, 1);
    fc(t1, W_fcg2, b_fcg2, xc, BB, 128, 1500, 256, 0);
    k_conv<<<250, 256, 0, stream>>>(target, embxt, W_conv, b_conv, xt);
    fc(xt, W_fcxt, b_fcxt, xc + 128, BB, 128, 560, 256, 0);
    fc(xc, W_fc1, b_fc1, f1, BB, 512, 256, 512, 1);
    k_out<<<(BB + 3) / 4, 256, 0, stream>>>(f1, W_out, b_out, out_sig);
}

// Round 6
// 628.026 us; speedup vs baseline: 3.2063x; 1.2661x over previous
//
#include <hip/hip_runtime.h>
#include <math.h>

#define NN 50000
#define EE 800000
#define BB 500
#define LL 42
#define NHEAD 10
#define FH 35
#define FG 350
#define ETOT (EE + NN)
#define NCHUNK ((NN + 511) / 512)

#define KPAD 384         // bf16 row stride for h / xg1 / h2
#define MPAD 50048       // M padded to multiple of 128
#define MB2  512         // padded batch rows for FC MFMA

typedef unsigned short ushort_t;
typedef __attribute__((ext_vector_type(8))) short short8v;
typedef __attribute__((ext_vector_type(4))) float float4v;

__device__ __forceinline__ float lrelu(float x) { return x > 0.f ? x : 0.2f * x; }

__device__ __forceinline__ ushort_t f2bf(float f) {
    unsigned int u = __float_as_uint(f);
    u += 0x7fffu + ((u >> 16) & 1u);      // round-to-nearest-even
    return (ushort_t)(u >> 16);
}
__device__ __forceinline__ float bflo(unsigned u) { return __uint_as_float(u << 16); }
__device__ __forceinline__ float bfhi(unsigned u) { return __uint_as_float(u & 0xffff0000u); }
__device__ __forceinline__ unsigned packbf(float a, float b) {
    return (unsigned)f2bf(a) | ((unsigned)f2bf(b) << 16);
}

__device__ __forceinline__ void async_cp16(const void* g, void* l) {
    __builtin_amdgcn_global_load_lds((const __attribute__((address_space(1))) unsigned int*)g,
                                     (__attribute__((address_space(3))) unsigned int*)l, 16, 0, 0);
}

// ---------------- graph prep ----------------
__global__ __launch_bounds__(256) void k_init(int* deg, int* cur) {
    int i = blockIdx.x * 256 + threadIdx.x;
    if (i < NN) { deg[i] = 1; cur[i] = 0; }   // deg=1 accounts for the self-loop
}

__global__ __launch_bounds__(256) void k_deg(const int* __restrict__ ei, int* deg) {
    int i = blockIdx.x * 256 + threadIdx.x;
    if (i < EE) atomicAdd(&deg[ei[EE + i]], 1);
}

__global__ __launch_bounds__(512) void k_scan1(const int* __restrict__ deg, int* part) {
    int i = blockIdx.x * 512 + threadIdx.x;
    int lane = threadIdx.x & 63, wv = threadIdx.x >> 6;
    int x = (i < NN) ? deg[i] : 0;
    #pragma unroll
    for (int d = 32; d; d >>= 1) x += __shfl_xor(x, d);
    __shared__ int wsum[8];
    if (lane == 0) wsum[wv] = x;
    __syncthreads();
    if (threadIdx.x == 0) {
        int s = 0;
        #pragma unroll
        for (int w = 0; w < 8; w++) s += wsum[w];
        part[blockIdx.x] = s;
    }
}

__global__ __launch_bounds__(64) void k_scan2(const int* __restrict__ part, int* pscan) {
    int l = threadIdx.x;
    int v0 = (l < NCHUNK) ? part[l] : 0;
    #pragma unroll
    for (int d = 1; d < 64; d <<= 1) { int t = __shfl_up(v0, d); if (l >= d) v0 += t; }
    int tot0 = __shfl(v0, 63);
    int v1 = (64 + l < NCHUNK) ? part[64 + l] : 0;
    #pragma unroll
    for (int d = 1; d < 64; d <<= 1) { int t = __shfl_up(v1, d); if (l >= d) v1 += t; }
    v1 += tot0;
    if (l < NCHUNK) pscan[l] = v0;
    if (64 + l < NCHUNK) pscan[64 + l] = v1;
}

__global__ __launch_bounds__(512) void k_scan3(const int* __restrict__ deg, const int* __restrict__ pscan,
                                               int* offs) {
    int i = blockIdx.x * 512 + threadIdx.x;
    int lane = threadIdx.x & 63, wv = threadIdx.x >> 6;
    int x = (i < NN) ? deg[i] : 0;
    int incl = x;
    #pragma unroll
    for (int d = 1; d < 64; d <<= 1) { int t = __shfl_up(incl, d); if (lane >= d) incl += t; }
    __shared__ int wtot[8];
    if (lane == 63) wtot[wv] = incl;
    __syncthreads();
    int woff = 0;
    for (int w = 0; w < wv; w++) woff += wtot[w];
    int base = (blockIdx.x == 0) ? 0 : pscan[blockIdx.x - 1];
    if (i < NN) offs[i] = base + woff + incl - x;   // exclusive prefix
}

__global__ __launch_bounds__(256) void k_scatter(const int* __restrict__ ei, const int* __restrict__ offs,
                                                 int* cur, int* csr_src) {
    int i = blockIdx.x * 256 + threadIdx.x;
    if (i < EE) {
        int s = ei[i], d = ei[EE + i];
        int slot = atomicAdd(&cur[d], 1);
        csr_src[offs[d] + slot] = s;
    } else if (i < ETOT) {
        int v = i - EE;
        int slot = atomicAdd(&cur[v], 1);
        csr_src[offs[v] + slot] = v;
    }
}

__global__ __launch_bounds__(256) void k_dinv(const int* __restrict__ deg, float* dinv) {
    int i = blockIdx.x * 256 + threadIdx.x;
    if (i < NN) dinv[i] = rsqrtf((float)deg[i]);
}

// ---------------- weight / input prep (f32 -> padded transposed bf16) ----------------
__global__ __launch_bounds__(256) void k_prep_x(const float* __restrict__ x, ushort_t* __restrict__ xb) {
    int i = blockIdx.x * 256 + threadIdx.x;
    if (i >= MPAD * 64) return;
    int r = i / 64, k = i % 64;
    float v = (r < NN && k < 35) ? x[r * 35 + k] : 0.f;
    xb[i] = f2bf(v);
}

__global__ __launch_bounds__(256) void k_prep_wgat(const float* __restrict__ W, ushort_t* __restrict__ Wt) {
    int i = blockIdx.x * 256 + threadIdx.x;
    if (i >= KPAD * 64) return;
    int n = i / 64, k = i % 64;
    float v = (n < FG && k < 35) ? W[k * FG + n] : 0.f;
    Wt[i] = f2bf(v);
}

__global__ __launch_bounds__(256) void k_prep_wgcn(const float* __restrict__ W, ushort_t* __restrict__ Wt) {
    int i = blockIdx.x * 256 + threadIdx.x;
    if (i >= KPAD * KPAD) return;
    int n = i / KPAD, k = i % KPAD;
    float v = (n < FG && k < FG) ? W[k * FG + n] : 0.f;
    Wt[i] = f2bf(v);
}

// generic: Wt[n*KP+k] = bf16(W[k*N+n]), zero-padded. read-coalesced over n.
__global__ __launch_bounds__(256) void k_prep_w(const float* __restrict__ W, ushort_t* __restrict__ Wt,
                                                int K, int N, int KP, int NP) {
    int i = blockIdx.x * 256 + threadIdx.x;
    if (i >= KP * NP) return;
    int k = i / NP, n = i % NP;
    float v = (k < K && n < N) ? W[(size_t)k * N + n] : 0.f;
    Wt[(size_t)n * KP + k] = f2bf(v);
}

// generic: dst[r*KP+k] = bf16(src[r*K+k]), zero-padded
__global__ __launch_bounds__(256) void k_cast_pad(const float* __restrict__ src, ushort_t* __restrict__ dst,
                                                  int M, int K, int MP, int KP) {
    int i = blockIdx.x * 256 + threadIdx.x;
    if (i >= MP * KP) return;
    int r = i / KP, k = i % KP;
    dst[i] = (r < M && k < K) ? f2bf(src[(size_t)r * K + k]) : (ushort_t)0;
}

// zero pad rows 50000..50047 of xg1b so GEMM A-staging reads defined data
__global__ __launch_bounds__(256) void k_zero_tail(ushort_t* xg1b) {
    int i = blockIdx.x * 256 + threadIdx.x;
    int total = (MPAD - NN) * KPAD;
    if (i < total) xg1b[(size_t)NN * KPAD + i] = 0;
}

// ---------------- bf16 MFMA GEMM: C = act(A[Mp,lda] @ Bt[Np,lda] + bias) ----------------
// tile 128x64, BK=64, 4 waves in 2x2, wave tile 64x32 (4x2 fragments of 16x16x32)
// cols >= Nv are written as 0 (keeps padded bf16 outputs consumable as next-layer A)
__global__ __launch_bounds__(256) void k_mfma(const ushort_t* __restrict__ A, const ushort_t* __restrict__ Bt,
                                              void* __restrict__ C, int M, int Nv, int ldc, int lda,
                                              int ksteps, const float* __restrict__ bias, int act, int bf16out) {
    __shared__ ushort_t As[128 * 64];
    __shared__ ushort_t Bs[64 * 64];
    int tid = threadIdx.x;
    int wid = tid >> 6, lane = tid & 63;
    int m0 = blockIdx.y * 128, n0 = blockIdx.x * 64;
    int wm0 = (wid >> 1) * 64, wn0 = (wid & 1) * 32;
    int srow = tid >> 3;              // staging: 8 lanes x 16B per row(128B)
    int scol = (tid & 7) * 8;
    float4v acc[4][2] = {{{0.f,0.f,0.f,0.f},{0.f,0.f,0.f,0.f}},
                         {{0.f,0.f,0.f,0.f},{0.f,0.f,0.f,0.f}},
                         {{0.f,0.f,0.f,0.f},{0.f,0.f,0.f,0.f}},
                         {{0.f,0.f,0.f,0.f},{0.f,0.f,0.f,0.f}}};
    int a_off = (wm0 + (lane & 15)) * 64 + (lane >> 4) * 8;
    int b_off = (wn0 + (lane & 15)) * 64 + (lane >> 4) * 8;
    for (int ks = 0; ks < ksteps; ks++) {
        int k0 = ks * 64;
        #pragma unroll
        for (int r = 0; r < 4; r++) {
            const ushort_t* g = A + (size_t)(m0 + r * 32 + srow) * lda + k0 + scol;
            async_cp16(g, As + (r * 256 + tid) * 8);
        }
        #pragma unroll
        for (int r = 0; r < 2; r++) {
            const ushort_t* g = Bt + (size_t)(n0 + r * 32 + srow) * lda + k0 + scol;
            async_cp16(g, Bs + (r * 256 + tid) * 8);
        }
        __syncthreads();
        #pragma unroll
        for (int kh = 0; kh < 2; kh++) {
            short8v b0 = *(const short8v*)&Bs[b_off + kh * 32];
            short8v b1 = *(const short8v*)&Bs[b_off + 16 * 64 + kh * 32];
            #pragma unroll
            for (int mi = 0; mi < 4; mi++) {
                short8v a = *(const short8v*)&As[a_off + mi * 16 * 64 + kh * 32];
                acc[mi][0] = __builtin_amdgcn_mfma_f32_16x16x32_bf16(a, b0, acc[mi][0], 0, 0, 0);
                acc[mi][1] = __builtin_amdgcn_mfma_f32_16x16x32_bf16(a, b1, acc[mi][1], 0, 0, 0);
            }
        }
        __syncthreads();
    }
    int lm = m0 + wm0 + (lane >> 4) * 4;
    int lc = n0 + wn0 + (lane & 15);
    #pragma unroll
    for (int mi = 0; mi < 4; mi++) {
        #pragma unroll
        for (int ni = 0; ni < 2; ni++) {
            int col = lc + ni * 16;
            float bv = (bias != nullptr && col < Nv) ? bias[col] : 0.f;
            #pragma unroll
            for (int r = 0; r < 4; r++) {
                int row = lm + mi * 16 + r;
                if (row >= M) continue;
                float v = acc[mi][ni][r] + bv;
                if (act) v = fmaxf(v, 0.f);
                if (col >= Nv) v = 0.f;
                if (bf16out) ((ushort_t*)C)[(size_t)row * ldc + col] = f2bf(v);
                else         ((float*)C)[(size_t)row * ldc + col] = v;
            }
        }
    }
}

// ---------------- GAT attention logits (bf16 h) ----------------
__global__ __launch_bounds__(256) void k_att(const ushort_t* __restrict__ hb, const float* __restrict__ att_s,
                                             const float* __restrict__ att_d, float* __restrict__ a_s,
                                             float* __restrict__ a_d) {
    int tid = blockIdx.x * 256 + threadIdx.x;
    if (tid >= NN * NHEAD) return;
    int n = tid / NHEAD, hd = tid % NHEAD;
    const ushort_t* hr = hb + (size_t)n * KPAD + hd * FH;
    const float* ws = att_s + hd * FH;
    const float* wd = att_d + hd * FH;
    float as = 0.f, ad = 0.f;
    #pragma unroll
    for (int c = 0; c < FH; c++) {
        float v = __uint_as_float(((unsigned)hr[c]) << 16);
        as += v * ws[c]; ad += v * wd[c];
    }
    a_s[tid] = as;
    a_d[tid] = ad;
}

// ---------------- GAT aggregate: wave per node, single pass, edge loop unrolled x2 ----------------
__global__ __launch_bounds__(256) void k_gat_agg(const ushort_t* __restrict__ hb, const float* __restrict__ a_s,
                                                 const float* __restrict__ a_d,
                                                 const int* __restrict__ csr_src,
                                                 const int* __restrict__ offs, const int* __restrict__ deg,
                                                 const float* __restrict__ b_gat,
                                                 ushort_t* __restrict__ xg1b, float* __restrict__ denArr) {
    int wid = (blockIdx.x * blockDim.x + threadIdx.x) >> 6;
    int lane = threadIdx.x & 63;
    if (wid >= NN) return;
    int o0 = offs[wid], d = deg[wid];
    bool mine = (lane < NHEAD);
    float adv = mine ? a_d[wid * NHEAD + lane] : 0.f;
    int hA0 = (2 * lane) / 35,       hA1 = (2 * lane + 1) / 35;
    int hB0 = (128 + 2 * lane) / 35, hB1 = (129 + 2 * lane) / 35;
    int hC0 = (256 + 2 * lane) / 35, hC1 = (257 + 2 * lane) / 35;   // ==10 for pad cols (h=0 there)
    float den = 0.f;
    float aL0 = 0.f, aH0 = 0.f, aL1 = 0.f, aH1 = 0.f, aL2 = 0.f, aH2 = 0.f;
    const unsigned* hb32 = (const unsigned*)hb;
    int i = 0;
    for (; i + 2 <= d; i += 2) {
        int s0 = csr_src[o0 + i], s1 = csr_src[o0 + i + 1];
        float as0 = mine ? a_s[s0 * NHEAD + lane] : 0.f;
        float as1 = mine ? a_s[s1 * NHEAD + lane] : 0.f;
        const unsigned* h0 = hb32 + (size_t)s0 * (KPAD / 2);
        const unsigned* h1 = hb32 + (size_t)s1 * (KPAD / 2);
        unsigned u00 = h0[lane], u01 = h0[lane + 64], u02 = h0[lane + 128];
        unsigned u10 = h1[lane], u11 = h1[lane + 64], u12 = h1[lane + 128];
        float ex0 = __expf(lrelu(as0 + adv));
        float ex1 = __expf(lrelu(as1 + adv));
        den += ex0 + ex1;
        aL0 += __shfl(ex0, hA0) * bflo(u00) + __shfl(ex1, hA0) * bflo(u10);
        aH0 += __shfl(ex0, hA1) * bfhi(u00) + __shfl(ex1, hA1) * bfhi(u10);
        aL1 += __shfl(ex0, hB0) * bflo(u01) + __shfl(ex1, hB0) * bflo(u11);
        aH1 += __shfl(ex0, hB1) * bfhi(u01) + __shfl(ex1, hB1) * bfhi(u11);
        aL2 += __shfl(ex0, hC0) * bflo(u02) + __shfl(ex1, hC0) * bflo(u12);
        aH2 += __shfl(ex0, hC1) * bfhi(u02) + __shfl(ex1, hC1) * bfhi(u12);
    }
    for (; i < d; i++) {
        int s = csr_src[o0 + i];
        float asv = mine ? a_s[s * NHEAD + lane] : 0.f;
        float ex = __expf(lrelu(asv + adv));
        den += ex;
        const unsigned* hr = hb32 + (size_t)s * (KPAD / 2);
        unsigned u0 = hr[lane], u1 = hr[lane + 64], u2 = hr[lane + 128];
        aL0 += __shfl(ex, hA0) * bflo(u0);  aH0 += __shfl(ex, hA1) * bfhi(u0);
        aL1 += __shfl(ex, hB0) * bflo(u1);  aH1 += __shfl(ex, hB1) * bfhi(u1);
        aL2 += __shfl(ex, hC0) * bflo(u2);  aH2 += __shfl(ex, hC1) * bfhi(u2);
    }
    float rden = 1.f / (den + 1e-16f);
    if (mine) denArr[wid * NHEAD + lane] = den;
    unsigned* orow = (unsigned*)(xg1b + (size_t)wid * KPAD);
    {
        int f = 2 * lane;
        float v0 = fmaxf(aL0 * __shfl(rden, hA0) + b_gat[f], 0.f);
        float v1 = fmaxf(aH0 * __shfl(rden, hA1) + b_gat[f + 1], 0.f);
        orow[lane] = packbf(v0, v1);
    }
    {
        int f = 128 + 2 * lane;
        float v0 = fmaxf(aL1 * __shfl(rden, hB0) + b_gat[f], 0.f);
        float v1 = fmaxf(aH1 * __shfl(rden, hB1) + b_gat[f + 1], 0.f);
        orow[lane + 64] = packbf(v0, v1);
    }
    {
        int f = 256 + 2 * lane;
        unsigned pv = 0;
        if (f < FG) {
            float v0 = fmaxf(aL2 * __shfl(rden, hC0) + b_gat[f], 0.f);
            float v1 = fmaxf(aH2 * __shfl(rden, hC1) + b_gat[f + 1], 0.f);
            pv = packbf(v0, v1);
        }
        orow[lane + 128] = pv;
    }
}

// ---------------- alpha in original edge order (coalesced writes; a_s/a_d/den are L2-resident) ----------------
__global__ __launch_bounds__(256) void k_alpha(const int* __restrict__ ei, const float* __restrict__ a_s,
                                               const float* __restrict__ a_d, const float* __restrict__ den,
                                               float* __restrict__ alphaOut) {
    int i = blockIdx.x * 256 + threadIdx.x;
    if (i >= ETOT * NHEAD) return;
    int e = i / NHEAD, hd = i % NHEAD;
    int s, dst;
    if (e < EE) { s = ei[e]; dst = ei[EE + e]; }
    else { s = dst = e - EE; }
    float ex = __expf(lrelu(a_s[s * NHEAD + hd] + a_d[dst * NHEAD + hd]));
    alphaOut[i] = ex / (den[dst * NHEAD + hd] + 1e-16f);
}

// ---------------- GCN aggregate: wave per node (bf16 h2 gathers), unrolled x2 ----------------
__global__ __launch_bounds__(256) void k_gcn_agg(const ushort_t* __restrict__ h2b,
                                                 const int* __restrict__ csr_src,
                                                 const int* __restrict__ offs, const int* __restrict__ deg,
                                                 const float* __restrict__ dinv, const float* __restrict__ b_gcn,
                                                 float* __restrict__ xg2) {
    int wid = (blockIdx.x * blockDim.x + threadIdx.x) >> 6;
    int lane = threadIdx.x & 63;
    if (wid >= NN) return;
    int o0 = offs[wid], d = deg[wid];
    float wv = dinv[wid];
    float aL0 = 0.f, aH0 = 0.f, aL1 = 0.f, aH1 = 0.f, aL2 = 0.f, aH2 = 0.f;
    const unsigned* h32 = (const unsigned*)h2b;
    int i = 0;
    for (; i + 2 <= d; i += 2) {
        int s0 = csr_src[o0 + i], s1 = csr_src[o0 + i + 1];
        float w0 = dinv[s0], w1 = dinv[s1];
        const unsigned* h0 = h32 + (size_t)s0 * (KPAD / 2);
        const unsigned* h1 = h32 + (size_t)s1 * (KPAD / 2);
        unsigned u00 = h0[lane], u01 = h0[lane + 64], u02 = h0[lane + 128];
        unsigned u10 = h1[lane], u11 = h1[lane + 64], u12 = h1[lane + 128];
        aL0 += w0 * bflo(u00) + w1 * bflo(u10);
        aH0 += w0 * bfhi(u00) + w1 * bfhi(u10);
        aL1 += w0 * bflo(u01) + w1 * bflo(u11);
        aH1 += w0 * bfhi(u01) + w1 * bfhi(u11);
        aL2 += w0 * bflo(u02) + w1 * bflo(u12);
        aH2 += w0 * bfhi(u02) + w1 * bfhi(u12);
    }
    for (; i < d; i++) {
        int s = csr_src[o0 + i];
        float ws = dinv[s];
        const unsigned* hr = h32 + (size_t)s * (KPAD / 2);
        unsigned u0 = hr[lane], u1 = hr[lane + 64], u2 = hr[lane + 128];
        aL0 += ws * bflo(u0);  aH0 += ws * bfhi(u0);
        aL1 += ws * bflo(u1);  aH1 += ws * bfhi(u1);
        aL2 += ws * bflo(u2);  aH2 += ws * bfhi(u2);
    }
    float* orow = xg2 + (size_t)wid * FG;
    {
        int f = 2 * lane;
        float2 v = { fmaxf(wv * aL0 + b_gcn[f], 0.f), fmaxf(wv * aH0 + b_gcn[f + 1], 0.f) };
        *(float2*)&orow[f] = v;
    }
    {
        int f = 128 + 2 * lane;
        float2 v = { fmaxf(wv * aL1 + b_gcn[f], 0.f), fmaxf(wv * aH1 + b_gcn[f + 1], 0.f) };
        *(float2*)&orow[f] = v;
    }
    {
        int f = 256 + 2 * lane;
        if (f < FG) {
            float2 v = { fmaxf(wv * aL2 + b_gcn[f], 0.f), fmaxf(wv * aH2 + b_gcn[f + 1], 0.f) };
            *(float2*)&orow[f] = v;
        }
    }
}

// ---------------- per-graph max+mean pool ----------------
__device__ __forceinline__ int lowerB(const int* a, int n, int key) {
    int lo = 0, hi = n;
    while (lo < hi) { int mid = (lo + hi) >> 1; if (a[mid] < key) lo = mid + 1; else hi = mid; }
    return lo;
}

__global__ __launch_bounds__(384) void k_pool(const float* __restrict__ xg2, const int* __restrict__ batch,
                                              float* __restrict__ pooled) {
    int g = blockIdx.x;
    int f = threadIdx.x;
    int s = lowerB(batch, NN, g);
    int e = lowerB(batch, NN, g + 1);
    if (f >= FG) return;
    float mx = -INFINITY, sm = 0.f;
    for (int n = s; n < e; n++) {
        float v = xg2[(size_t)n * FG + f];
        mx = fmaxf(mx, v);
        sm += v;
    }
    int cnt = e - s;
    pooled[g * 700 + f] = mx;
    pooled[g * 700 + FG + f] = sm / fmaxf((float)cnt, 1.f);
}

// ---------------- protein conv branch: LDS-resident, 2 proteins per block ----------------
__global__ __launch_bounds__(256) void k_conv(const int* __restrict__ target, const float* __restrict__ emb,
                                              const float* __restrict__ Wc, const float* __restrict__ bc,
                                              float* __restrict__ xt) {
    __shared__ float embL[26 * 132];        // rows padded to 132 floats
    __shared__ float WL[16 * 8 * 128];      // WL[f][k][e] = Wc[f][e][k]
    __shared__ int   tgL[2 * LL];
    int tid = threadIdx.x;
    int b0 = blockIdx.x * 2;
    for (int i = tid; i < 26 * 128; i += 256) {
        int r = i >> 7, e = i & 127;
        embL[r * 132 + e] = emb[i];
    }
    for (int i = tid; i < 16384; i += 256) {
        int f = i >> 10, rem = i & 1023, k = rem >> 7, e = rem & 127;
        WL[i] = Wc[f * 1024 + e * 8 + k];
    }
    if (tid < 2 * LL) tgL[tid] = target[b0 * LL + tid];
    __syncthreads();
    #pragma unroll
    for (int pass = 0; pass < 2; pass++) {
        int r = tid + pass * 256;
        if (r >= 280) break;
        int bl = r / 140, rem = r % 140;
        int fq = rem / 35, t = rem % 35;
        const int* tg = &tgL[bl * LL];
        float ac0 = 0.f, ac1 = 0.f, ac2 = 0.f, ac3 = 0.f;
        for (int k = 0; k < 8; k++) {
            const float* er = &embL[tg[t + k] * 132];
            const float* w0 = &WL[((fq * 4 + 0) * 8 + k) * 128];
            const float* w1 = &WL[((fq * 4 + 1) * 8 + k) * 128];
            const float* w2 = &WL[((fq * 4 + 2) * 8 + k) * 128];
            const float* w3 = &WL[((fq * 4 + 3) * 8 + k) * 128];
            #pragma unroll 8
            for (int e = 0; e < 128; e += 4) {
                float4 a = *(const float4*)&er[e];
                float4 q0 = *(const float4*)&w0[e];
                float4 q1 = *(const float4*)&w1[e];
                float4 q2 = *(const float4*)&w2[e];
                float4 q3 = *(const float4*)&w3[e];
                ac0 += a.x * q0.x + a.y * q0.y + a.z * q0.z + a.w * q0.w;
                ac1 += a.x * q1.x + a.y * q1.y + a.z * q1.z + a.w * q1.w;
                ac2 += a.x * q2.x + a.y * q2.y + a.z * q2.z + a.w * q2.w;
                ac3 += a.x * q3.x + a.y * q3.y + a.z * q3.z + a.w * q3.w;
            }
        }
        int b = b0 + bl, fb = fq * 4;
        xt[b * 560 + (fb + 0) * 35 + t] = ac0 + bc[fb + 0];
        xt[b * 560 + (fb + 1) * 35 + t] = ac1 + bc[fb + 1];
        xt[b * 560 + (fb + 2) * 35 + t] = ac2 + bc[fb + 2];
        xt[b * 560 + (fb + 3) * 35 + t] = ac3 + bc[fb + 3];
    }
}

// ---------------- final dot + sigmoid ----------------
__global__ __launch_bounds__(256) void k_out(const float* __restrict__ f1, const float* __restrict__ W_out,
                                             const float* __restrict__ b_out, float* __restrict__ out) {
    int wid = (blockIdx.x * blockDim.x + threadIdx.x) >> 6;
    int lane = threadIdx.x & 63;
    if (wid >= BB) return;
    const float* xr = f1 + (size_t)wid * 512;
    float acc = 0.f;
    #pragma unroll
    for (int k = 0; k < 8; k++) acc += xr[lane + k * 64] * W_out[lane + k * 64];
    #pragma unroll
    for (int d = 32; d; d >>= 1) acc += __shfl_xor(acc, d);
    if (lane == 0) out[wid] = 1.f / (1.f + __expf(-(acc + b_out[0])));
}

// ---------------- host launcher ----------------
extern "C" void kernel_launch(void* const* d_in, const int* in_sizes, int n_in,
                              void* d_out, int out_size, void* d_ws, size_t ws_size,
                              hipStream_t stream) {
    const float* x      = (const float*)d_in[0];
    const int*   ei     = (const int*)d_in[1];
    const int*   batch  = (const int*)d_in[2];
    const int*   target = (const int*)d_in[3];
    const float* W_gat  = (const float*)d_in[4];
    const float* att_s  = (const float*)d_in[5];
    const float* att_d  = (const float*)d_in[6];
    const float* b_gat  = (const float*)d_in[7];
    const float* W_gcn  = (const float*)d_in[8];
    const float* b_gcn  = (const float*)d_in[9];
    const float* W_fcg1 = (const float*)d_in[10];
    const float* b_fcg1 = (const float*)d_in[11];
    const float* W_fcg2 = (const float*)d_in[12];
    const float* b_fcg2 = (const float*)d_in[13];
    const float* embxt  = (const float*)d_in[14];
    const float* W_conv = (const float*)d_in[15];
    const float* b_conv = (const float*)d_in[16];
    const float* W_fcxt = (const float*)d_in[17];
    const float* b_fcxt = (const float*)d_in[18];
    const float* W_fc1  = (const float*)d_in[19];
    const float* b_fc1  = (const float*)d_in[20];
    const float* W_out  = (const float*)d_in[21];
    const float* b_out  = (const float*)d_in[22];

    float* out_sig  = (float*)d_out;          // [500]
    float* alphaOut = (float*)d_out + BB;     // [850000 * 10]

    size_t o = 0;
    auto alloc = [&](size_t bytes) -> void* {
        o = (o + 255) & ~(size_t)255;
        void* p = (char*)d_ws + o;
        o += bytes;
        return p;
    };
    int*   deg     = (int*)alloc((size_t)NN * 4);
    int*   cur     = (int*)alloc((size_t)NN * 4);
    int*   offs    = (int*)alloc((size_t)NN * 4);
    int*   part    = (int*)alloc(128 * 4);
    int*   pscan   = (int*)alloc(128 * 4);
    int*   csr_src = (int*)alloc((size_t)ETOT * 4);
    float* dinv    = (float*)alloc((size_t)NN * 4);
    float* a_s     = (float*)alloc((size_t)NN * NHEAD * 4);
    float* a_d     = (float*)alloc((size_t)NN * NHEAD * 4);
    float* denArr  = (float*)alloc((size_t)NN * NHEAD * 4);
    ushort_t* xb16 = (ushort_t*)alloc((size_t)MPAD * 64 * 2);
    ushort_t* WtGA = (ushort_t*)alloc((size_t)KPAD * 64 * 2);
    ushort_t* WtGC = (ushort_t*)alloc((size_t)KPAD * KPAD * 2);
    ushort_t* WtF1 = (ushort_t*)alloc((size_t)1536 * 704 * 2);   // W_fcg1^T [1536][704]
    ushort_t* WtF2 = (ushort_t*)alloc((size_t)128 * 1536 * 2);   // W_fcg2^T [128][1536]
    ushort_t* WtFX = (ushort_t*)alloc((size_t)128 * 576 * 2);    // W_fcxt^T [128][576]
    ushort_t* WtFC = (ushort_t*)alloc((size_t)512 * 256 * 2);    // W_fc1^T  [512][256]
    float* pooled  = (float*)alloc((size_t)BB * 700 * 4);
    ushort_t* pooledb = (ushort_t*)alloc((size_t)MB2 * 704 * 2);
    ushort_t* t1b  = (ushort_t*)alloc((size_t)MB2 * 1536 * 2);
    float* xt      = (float*)alloc((size_t)BB * 560 * 4);
    ushort_t* xtb  = (ushort_t*)alloc((size_t)MB2 * 576 * 2);
    ushort_t* xcb  = (ushort_t*)alloc((size_t)MB2 * 256 * 2);
    float* f1      = (float*)alloc((size_t)MB2 * 512 * 4);
    ushort_t* hb   = (ushort_t*)alloc((size_t)MPAD * KPAD * 2);   // h (GAT), later h2 (GCN out)
    char*  R2      = (char*)alloc((size_t)NN * FG * 4);           // 70 MB aliased region
    ushort_t* xg1b = (ushort_t*)R2;                               // [MPAD][KPAD] bf16 (38.4 MB)
    float* xg2     = (float*)R2;                                  // [NN][FG] f32, after xg1b dead
    (void)ws_size; (void)n_in; (void)in_sizes; (void)out_size;

    auto mfma = [&](const ushort_t* A, const ushort_t* Bt, void* C, const float* bias,
                    int M2, int Nv, int NP, int ldc, int KP, int act, int bf16out) {
        dim3 g(NP / 64, M2 / 128);
        k_mfma<<<g, 256, 0, stream>>>(A, Bt, C, M2, Nv, ldc, KP, KP / 64, bias, act, bf16out);
    };

    // graph prep
    k_init<<<(NN + 255) / 256, 256, 0, stream>>>(deg, cur);
    k_deg<<<(EE + 255) / 256, 256, 0, stream>>>(ei, deg);
    k_scan1<<<NCHUNK, 512, 0, stream>>>(deg, part);
    k_scan2<<<1, 64, 0, stream>>>(part, pscan);
    k_scan3<<<NCHUNK, 512, 0, stream>>>(deg, pscan, offs);
    k_scatter<<<(ETOT + 255) / 256, 256, 0, stream>>>(ei, offs, cur, csr_src);
    k_dinv<<<(NN + 255) / 256, 256, 0, stream>>>(deg, dinv);

    // bf16 prep (inputs + all weights)
    k_prep_x<<<(MPAD * 64 + 255) / 256, 256, 0, stream>>>(x, xb16);
    k_prep_wgat<<<(KPAD * 64 + 255) / 256, 256, 0, stream>>>(W_gat, WtGA);
    k_prep_wgcn<<<(KPAD * KPAD + 255) / 256, 256, 0, stream>>>(W_gcn, WtGC);
    k_prep_w<<<(704 * 1536 + 255) / 256, 256, 0, stream>>>(W_fcg1, WtF1, 700, 1500, 704, 1536);
    k_prep_w<<<(1536 * 128 + 255) / 256, 256, 0, stream>>>(W_fcg2, WtF2, 1500, 128, 1536, 128);
    k_prep_w<<<(576 * 128 + 255) / 256, 256, 0, stream>>>(W_fcxt, WtFX, 560, 128, 576, 128);
    k_prep_w<<<(256 * 512 + 255) / 256, 256, 0, stream>>>(W_fc1, WtFC, 256, 512, 256, 512);
    k_zero_tail<<<((MPAD - NN) * KPAD + 255) / 256, 256, 0, stream>>>(xg1b);

    // GAT: h = x @ W_gat  (bf16 MFMA, bf16 out)
    mfma(xb16, WtGA, hb, nullptr, MPAD, KPAD, KPAD, KPAD, 64, 0, 1);
    k_att<<<(NN * NHEAD + 255) / 256, 256, 0, stream>>>(hb, att_s, att_d, a_s, a_d);
    k_gat_agg<<<(NN + 3) / 4, 256, 0, stream>>>(hb, a_s, a_d, csr_src, offs, deg, b_gat, xg1b, denArr);
    k_alpha<<<(ETOT * NHEAD + 255) / 256, 256, 0, stream>>>(ei, a_s, a_d, denArr, alphaOut);

    // GCN: h2 = xg1 @ W_gcn (bf16 MFMA, bf16 out, overwrites hb region)
    mfma(xg1b, WtGC, hb, nullptr, MPAD, KPAD, KPAD, KPAD, KPAD, 0, 1);
    k_gcn_agg<<<(NN + 3) / 4, 256, 0, stream>>>(hb, csr_src, offs, deg, dinv, b_gcn, xg2);

    // pool + FC stacks (all FC layers via bf16 MFMA)
    k_pool<<<BB, 384, 0, stream>>>(xg2, batch, pooled);
    k_cast_pad<<<(MB2 * 704 + 255) / 256, 256, 0, stream>>>(pooled, pooledb, BB, 700, MB2, 704);
    mfma(pooledb, WtF1, t1b, b_fcg1, MB2, 1500, 1536, 1536, 704, 1, 1);      // t1 = relu(pooled@W1+b)
    mfma(t1b, WtF2, xcb, b_fcg2, MB2, 128, 128, 256, 1536, 0, 1);            // xc[:, :128]
    k_conv<<<250, 256, 0, stream>>>(target, embxt, W_conv, b_conv, xt);
    k_cast_pad<<<(MB2 * 576 + 255) / 256, 256, 0, stream>>>(xt, xtb, BB, 560, MB2, 576);
    mfma(xtb, WtFX, xcb + 128, b_fcxt, MB2, 128, 128, 256, 576, 0, 1);       // xc[:, 128:]
    mfma(xcb, WtFC, f1, b_fc1, MB2, 512, 512, 512, 256, 1, 0);               // f1 = relu(xc@Wfc1+b)
    k_out<<<(BB + 3) / 4, 256, 0, stream>>>(f1, W_out, b_out, out_sig);
}